// Round 16
// baseline (192.330 us; speedup 1.0000x reference)
//
#include <hip/hip_runtime.h>
#include <math.h>

#define NN 100000
#define NE 1600000
#define BSZ 64                          // dst nodes per bucket
#define NBUCK ((NN + BSZ - 1) / BSZ)    // 1563
#define NBLK 256                        // scatter blocks / hist columns
#define CHUNK ((NE + NBLK - 1) / NBLK)  // 6250 edges per block
#define NH (NBUCK * NBLK)               // 400128 hist entries
#define NSB ((NH + 1023) / 1024)        // 391 scan blocks

typedef unsigned int uint;
typedef unsigned short ushort_t;
typedef float f32x2 __attribute__((ext_vector_type(2)));
typedef float f32x4 __attribute__((ext_vector_type(4)));
typedef short s16x8 __attribute__((ext_vector_type(8)));

union U4S8 { uint4 u; s16x8 s; };

// bf16 helpers (RNE pack)
__device__ inline uint bf16_1(float f) {
  uint u = __float_as_uint(f);
  return (u + 0x7FFFu + ((u >> 16) & 1u)) >> 16;
}
__device__ inline uint bf16_2(float lo, float hi) {
  return bf16_1(lo) | (bf16_1(hi) << 16);
}

__device__ inline f32x4 mfma_bf16(uint4 a, uint4 b, f32x4 c) {
  U4S8 ua, ub; ua.u = a; ub.u = b;
  return __builtin_amdgcn_mfma_f32_16x16x32_bf16(ua.s, ub.s, c, 0, 0, 0);
}

// ---------------------------------------------------------------------------
// x (fp32 [NN][128]) -> xh (bf16, [NN][64] uints) AND xq (fp8 e4m3,
// [NN][32] uints).
// ---------------------------------------------------------------------------
__global__ __launch_bounds__(256) void tobf16_kernel(
    const float* __restrict__ x, uint* __restrict__ xh,
    uint* __restrict__ xq) {
  int i = blockIdx.x * 256 + threadIdx.x;
  if (i >= NN * 16) return;
  const float4* p = (const float4*)x + (size_t)i * 2;
  float4 a = p[0], b = p[1];
  uint4 o;
  o.x = bf16_2(a.x, a.y);
  o.y = bf16_2(a.z, a.w);
  o.z = bf16_2(b.x, b.y);
  o.w = bf16_2(b.z, b.w);
  ((uint4*)xh)[i] = o;
  int q0 = __builtin_amdgcn_cvt_pk_fp8_f32(a.x, a.y, 0, false);
  q0 = __builtin_amdgcn_cvt_pk_fp8_f32(a.z, a.w, q0, true);
  int q1 = __builtin_amdgcn_cvt_pk_fp8_f32(b.x, b.y, 0, false);
  q1 = __builtin_amdgcn_cvt_pk_fp8_f32(b.z, b.w, q1, true);
  uint2 oq; oq.x = (uint)q0; oq.y = (uint)q1;
  int r = i >> 4;
  int u = (i & 15) * 2;
  *(uint2*)(xq + (size_t)r * 32 + u) = oq;
}

// ---------------------------------------------------------------------------
// Weight prep (fused): w1t (16384 entries) then w2t (2048 entries).
// ---------------------------------------------------------------------------
__global__ __launch_bounds__(256) void prep_w_kernel(
    const float* __restrict__ ws1, const float* __restrict__ wn1,
    const float* __restrict__ ws2, const float* __restrict__ wn2,
    uint* __restrict__ w1t, uint* __restrict__ w2t) {
  int idx = blockIdx.x * 256 + threadIdx.x;
  if (idx < 128 * 128) {
    int col = idx >> 7, ku = idx & 127;
    int k = ku * 2;
    const float* w = (k < 128) ? ws1 : wn1;
    int kk = (k < 128) ? k : (k - 128);
    w1t[idx] = bf16_2(w[(size_t)kk * 128 + col], w[(size_t)(kk + 1) * 128 + col]);
  } else if (idx < 128 * 128 + 32 * 64) {
    int j = idx - 128 * 128;
    int col = j >> 6, ku = j & 63;
    int k = ku * 2;
    const float* w = (col < 16) ? ws2 : wn2;
    int c = col & 15;
    w2t[j] = bf16_2(w[(size_t)k * 16 + c], w[(size_t)(k + 1) * 16 + c]);
  }
}

// ---------------------------------------------------------------------------
// Pass A: per-block bucket histogram, LDS atomics only, coalesced output.
// ---------------------------------------------------------------------------
__global__ __launch_bounds__(1024) void histA_kernel(
    const int* __restrict__ dst, int* __restrict__ hist2) {
  __shared__ int lh[NBUCK];
  int tid = threadIdx.x;
  int b = blockIdx.x;
  for (int i = tid; i < NBUCK; i += 1024) lh[i] = 0;
  __syncthreads();
  int e0 = b * CHUNK, e1 = min(e0 + CHUNK, NE);
  for (int e = e0 + tid; e < e1; e += 1024) {
    atomicAdd(&lh[dst[e] >> 6], 1);
  }
  __syncthreads();
  for (int i = tid; i < NBUCK; i += 1024)
    hist2[(size_t)b * NBUCK + i] = lh[i];
}

// ---------------------------------------------------------------------------
// Transpose hist2[NBLK][NBUCK] -> hist[NBUCK][NBLK].
// ---------------------------------------------------------------------------
__global__ __launch_bounds__(1024) void transpose_kernel(
    const int* __restrict__ hist2, int* __restrict__ hist) {
  __shared__ int t[32][33];
  int tx = threadIdx.x & 31, ty = threadIdx.x >> 5;
  int i = blockIdx.x * 32 + tx;
  int b = blockIdx.y * 32 + ty;
  if (i < NBUCK) t[ty][tx] = hist2[(size_t)b * NBUCK + i];
  __syncthreads();
  int i2 = blockIdx.x * 32 + ty;
  int b2 = blockIdx.y * 32 + tx;
  if (i2 < NBUCK) hist[(size_t)i2 * NBLK + b2] = t[tx][ty];
}

// ---------------------------------------------------------------------------
// Multi-block exclusive scan over hist[NH] (in-place), 3 kernels.
// ---------------------------------------------------------------------------
__global__ __launch_bounds__(1024) void scan_sums_kernel(
    const int* __restrict__ hist, int* __restrict__ sums) {
  __shared__ int sdata[1024];
  int i = blockIdx.x * 1024 + threadIdx.x;
  sdata[threadIdx.x] = (i < NH) ? hist[i] : 0;
  __syncthreads();
#pragma unroll
  for (int s = 512; s > 0; s >>= 1) {
    if (threadIdx.x < s) sdata[threadIdx.x] += sdata[threadIdx.x + s];
    __syncthreads();
  }
  if (threadIdx.x == 0) sums[blockIdx.x] = sdata[0];
}

__global__ __launch_bounds__(512) void scan_tops_kernel(int* __restrict__ sums) {
  __shared__ int buf[2][512];
  int tid = threadIdx.x;
  int v = (tid < NSB) ? sums[tid] : 0;
  buf[0][tid] = v;
  __syncthreads();
  int pp = 0;
#pragma unroll
  for (int d = 1; d < 512; d <<= 1) {
    buf[pp ^ 1][tid] = buf[pp][tid] + ((tid >= d) ? buf[pp][tid - d] : 0);
    pp ^= 1;
    __syncthreads();
  }
  if (tid < NSB) sums[tid] = buf[pp][tid] - v;  // exclusive
}

__global__ __launch_bounds__(1024) void scan_apply_kernel(
    int* __restrict__ hist, const int* __restrict__ sums) {
  __shared__ int buf[2][1024];
  int tid = threadIdx.x;
  int i = blockIdx.x * 1024 + tid;
  int v = (i < NH) ? hist[i] : 0;
  buf[0][tid] = v;
  __syncthreads();
  int pp = 0;
#pragma unroll
  for (int d = 1; d < 1024; d <<= 1) {
    buf[pp ^ 1][tid] = buf[pp][tid] + ((tid >= d) ? buf[pp][tid - d] : 0);
    pp ^= 1;
    __syncthreads();
  }
  if (i < NH) hist[i] = sums[blockIdx.x] + buf[pp][tid] - v;  // exclusive
}

// ---------------------------------------------------------------------------
// Pass C: contention-free scatter via scanned per-(bucket,block) cursors.
// ---------------------------------------------------------------------------
__global__ __launch_bounds__(1024) void scatter3_kernel(
    const int* __restrict__ src, const int* __restrict__ dst,
    const int* __restrict__ scanned, unsigned int* __restrict__ ebuf) {
  __shared__ int cur[NBUCK];
  int tid = threadIdx.x;
  int b = blockIdx.x;
  for (int i = tid; i < NBUCK; i += 1024) cur[i] = scanned[i * NBLK + b];
  __syncthreads();
  int e0 = b * CHUNK, e1 = min(e0 + CHUNK, NE);
  for (int e = e0 + tid; e < e1; e += 1024) {
    int d = dst[e];
    int p = atomicAdd(&cur[d >> 6], 1);
    ebuf[p] = ((unsigned int)(d & 63) << 17) | (unsigned int)src[e];
  }
}

// ---------------------------------------------------------------------------
// Per-bucket counting sort, two-pass (computes deg + off, no global atomics).
// ---------------------------------------------------------------------------
__global__ __launch_bounds__(256) void bucket_sort_kernel(
    const unsigned int* __restrict__ ebuf, const int* __restrict__ scanned,
    int* __restrict__ deg, int* __restrict__ off, int* __restrict__ perm) {
  __shared__ int cnt[BSZ];
  __shared__ int loc_off[BSZ];
  int tid = threadIdx.x;
  int b = blockIdx.x;
  int e0 = scanned[b * NBLK];
  int e1 = (b + 1 < NBUCK) ? scanned[(b + 1) * NBLK] : NE;

  if (tid < BSZ) cnt[tid] = 0;
  __syncthreads();
  for (int e = e0 + tid; e < e1; e += 256)
    atomicAdd(&cnt[ebuf[e] >> 17], 1);
  __syncthreads();

  if (tid < BSZ) {   // threads 0..63 = one wave
    int v = cnt[tid];
    int incl = v;
#pragma unroll
    for (int d = 1; d < 64; d <<= 1) {
      int t = __shfl_up(incl, d);
      if (tid >= d) incl += t;
    }
    int excl = incl - v;
    loc_off[tid] = e0 + excl;
    int node = b * BSZ + tid;
    if (node < NN) { off[node] = e0 + excl; deg[node] = v; }
    cnt[tid] = 0;
  }
  __syncthreads();

  for (int e = e0 + tid; e < e1; e += 256) {
    unsigned int pk = ebuf[e];
    int dl = pk >> 17;
    int p = loc_off[dl] + atomicAdd(&cnt[dl], 1);
    perm[p] = (int)(pk & 0x1FFFF);
  }
}

// ---------------------------------------------------------------------------
// Layer-1 mean aggregation rev3: one wave per node.
// Lane q (0..15) owns uint2 q (feats 8q..8q+7); 4 edge slots (lane>>4);
// unroll x8 -> 8 independent 512B wave-gathers in flight.
// Reduce = 2 shfl levels per node. Coalesced 256B write.
// ---------------------------------------------------------------------------
__global__ __launch_bounds__(256) void mean1_kernel(
    const uint* __restrict__ xq, const int* __restrict__ off,
    const int* __restrict__ deg, const int* __restrict__ perm,
    uint* __restrict__ m1h) {
  int node = blockIdx.x * 4 + (threadIdx.x >> 6);
  int lane = threadIdx.x & 63;
  if (node >= NN) return;
  int o = off[node], dg = deg[node];
  int slot = lane >> 4;   // 4 edge slots
  int q = lane & 15;      // uint2 within the 32-uint fp8 row
  f32x2 a0 = {0.f, 0.f}, a1 = {0.f, 0.f}, a2 = {0.f, 0.f}, a3 = {0.f, 0.f};
  const uint* xb = xq + q * 2;
  int j = slot;
  for (; j + 28 < dg; j += 32) {   // 8 gathers in flight per lane
    int sA = perm[o + j];
    int sB = perm[o + j + 4];
    int sC = perm[o + j + 8];
    int sD = perm[o + j + 12];
    int sE = perm[o + j + 16];
    int sF = perm[o + j + 20];
    int sG = perm[o + j + 24];
    int sH = perm[o + j + 28];
    uint2 vA = *(const uint2*)(xb + (size_t)sA * 32);
    uint2 vB = *(const uint2*)(xb + (size_t)sB * 32);
    uint2 vC = *(const uint2*)(xb + (size_t)sC * 32);
    uint2 vD = *(const uint2*)(xb + (size_t)sD * 32);
    uint2 vE = *(const uint2*)(xb + (size_t)sE * 32);
    uint2 vF = *(const uint2*)(xb + (size_t)sF * 32);
    uint2 vG = *(const uint2*)(xb + (size_t)sG * 32);
    uint2 vH = *(const uint2*)(xb + (size_t)sH * 32);
    a0 += __builtin_amdgcn_cvt_pk_f32_fp8(vA.x, 0);
    a1 += __builtin_amdgcn_cvt_pk_f32_fp8(vA.x, 1);
    a2 += __builtin_amdgcn_cvt_pk_f32_fp8(vA.y, 0);
    a3 += __builtin_amdgcn_cvt_pk_f32_fp8(vA.y, 1);
    a0 += __builtin_amdgcn_cvt_pk_f32_fp8(vB.x, 0);
    a1 += __builtin_amdgcn_cvt_pk_f32_fp8(vB.x, 1);
    a2 += __builtin_amdgcn_cvt_pk_f32_fp8(vB.y, 0);
    a3 += __builtin_amdgcn_cvt_pk_f32_fp8(vB.y, 1);
    a0 += __builtin_amdgcn_cvt_pk_f32_fp8(vC.x, 0);
    a1 += __builtin_amdgcn_cvt_pk_f32_fp8(vC.x, 1);
    a2 += __builtin_amdgcn_cvt_pk_f32_fp8(vC.y, 0);
    a3 += __builtin_amdgcn_cvt_pk_f32_fp8(vC.y, 1);
    a0 += __builtin_amdgcn_cvt_pk_f32_fp8(vD.x, 0);
    a1 += __builtin_amdgcn_cvt_pk_f32_fp8(vD.x, 1);
    a2 += __builtin_amdgcn_cvt_pk_f32_fp8(vD.y, 0);
    a3 += __builtin_amdgcn_cvt_pk_f32_fp8(vD.y, 1);
    a0 += __builtin_amdgcn_cvt_pk_f32_fp8(vE.x, 0);
    a1 += __builtin_amdgcn_cvt_pk_f32_fp8(vE.x, 1);
    a2 += __builtin_amdgcn_cvt_pk_f32_fp8(vE.y, 0);
    a3 += __builtin_amdgcn_cvt_pk_f32_fp8(vE.y, 1);
    a0 += __builtin_amdgcn_cvt_pk_f32_fp8(vF.x, 0);
    a1 += __builtin_amdgcn_cvt_pk_f32_fp8(vF.x, 1);
    a2 += __builtin_amdgcn_cvt_pk_f32_fp8(vF.y, 0);
    a3 += __builtin_amdgcn_cvt_pk_f32_fp8(vF.y, 1);
    a0 += __builtin_amdgcn_cvt_pk_f32_fp8(vG.x, 0);
    a1 += __builtin_amdgcn_cvt_pk_f32_fp8(vG.x, 1);
    a2 += __builtin_amdgcn_cvt_pk_f32_fp8(vG.y, 0);
    a3 += __builtin_amdgcn_cvt_pk_f32_fp8(vG.y, 1);
    a0 += __builtin_amdgcn_cvt_pk_f32_fp8(vH.x, 0);
    a1 += __builtin_amdgcn_cvt_pk_f32_fp8(vH.x, 1);
    a2 += __builtin_amdgcn_cvt_pk_f32_fp8(vH.y, 0);
    a3 += __builtin_amdgcn_cvt_pk_f32_fp8(vH.y, 1);
  }
  for (; j < dg; j += 4) {
    int s = perm[o + j];
    uint2 v = *(const uint2*)(xb + (size_t)s * 32);
    a0 += __builtin_amdgcn_cvt_pk_f32_fp8(v.x, 0);
    a1 += __builtin_amdgcn_cvt_pk_f32_fp8(v.x, 1);
    a2 += __builtin_amdgcn_cvt_pk_f32_fp8(v.y, 0);
    a3 += __builtin_amdgcn_cvt_pk_f32_fp8(v.y, 1);
  }
  // reduce across the 4 edge slots (xor 16, 32)
#pragma unroll
  for (int d = 16; d <= 32; d <<= 1) {
    a0.x += __shfl_xor(a0.x, d); a0.y += __shfl_xor(a0.y, d);
    a1.x += __shfl_xor(a1.x, d); a1.y += __shfl_xor(a1.y, d);
    a2.x += __shfl_xor(a2.x, d); a2.y += __shfl_xor(a2.y, d);
    a3.x += __shfl_xor(a3.x, d); a3.y += __shfl_xor(a3.y, d);
  }
  if (slot == 0) {
    float rd = 1.0f / fmaxf((float)dg, 1.0f);
    uint4 o4;
    o4.x = bf16_2(a0.x * rd, a0.y * rd);   // feats 8q..8q+1
    o4.y = bf16_2(a1.x * rd, a1.y * rd);   // feats 8q+2..8q+3
    o4.z = bf16_2(a2.x * rd, a2.y * rd);   // feats 8q+4..8q+5
    o4.w = bf16_2(a3.x * rd, a3.y * rd);   // feats 8q+6..8q+7
    *(uint4*)(m1h + (size_t)node * 64 + q * 4) = o4;
  }
}

// ---------------------------------------------------------------------------
// GEMM1 (MFMA bf16, LDS-staged B): h = relu([xh | m1h] @ w1t^T + b1).
// ---------------------------------------------------------------------------
__global__ __launch_bounds__(256) void gemm1_mfma_kernel(
    const uint* __restrict__ xh, const uint* __restrict__ m1h,
    const uint* __restrict__ w1t, const float* __restrict__ b1,
    ushort_t* __restrict__ hout) {
  __shared__ uint lds_w[128 * 128];   // 64 KB
  int tid = threadIdx.x;

#pragma unroll
  for (int i = 0; i < 16; i++) {
    int g = tid + i * 256;
    int row = g >> 5, c = g & 31;
    uint4 v = ((const uint4*)w1t)[g];
    int cs = c ^ (row & 7);
    *(uint4*)&lds_w[row * 128 + cs * 4] = v;
  }
  __syncthreads();

  int wv = tid >> 6;
  int lane = tid & 63;
  int lr = lane & 15, lk = lane >> 4;
  int r0 = blockIdx.x * 256 + wv * 64;
  if (r0 >= NN) return;   // after the only barrier

  f32x4 acc[4][8];
#pragma unroll
  for (int i = 0; i < 4; i++)
#pragma unroll
    for (int j = 0; j < 8; j++) acc[i][j] = (f32x4){0.f, 0.f, 0.f, 0.f};

#pragma unroll
  for (int ks = 0; ks < 8; ks++) {
    const uint* A = (ks < 4) ? xh : m1h;
    int ku = (ks & 3) * 16 + lk * 4;
    uint4 a[4];
#pragma unroll
    for (int rt = 0; rt < 4; rt++) {
      int row = r0 + rt * 16 + lr;
      if (row >= NN) row = NN - 1;
      a[rt] = *(const uint4*)(A + (size_t)row * 64 + ku);
    }
    int cbase = ks * 4 + lk;
#pragma unroll
    for (int ct = 0; ct < 8; ct++) {
      int brow = ct * 16 + lr;
      int cs = cbase ^ (lr & 7);
      uint4 bu = *(const uint4*)&lds_w[brow * 128 + cs * 4];
#pragma unroll
      for (int rt = 0; rt < 4; rt++)
        acc[rt][ct] = mfma_bf16(a[rt], bu, acc[rt][ct]);
    }
  }

  float bias[8];
#pragma unroll
  for (int ct = 0; ct < 8; ct++) bias[ct] = b1[ct * 16 + lr];

#pragma unroll
  for (int rt = 0; rt < 4; rt++) {
#pragma unroll
    for (int r = 0; r < 4; r++) {
      int row = r0 + rt * 16 + lk * 4 + r;
      if (row < NN) {
#pragma unroll
        for (int ct = 0; ct < 8; ct++) {
          int col = ct * 16 + lr;
          float v = fmaxf(acc[rt][ct][r] + bias[ct], 0.0f);
          hout[(size_t)row * 128 + col] = (ushort_t)bf16_1(v);
        }
      }
    }
  }
}

// ---------------------------------------------------------------------------
// GEMM2 (MFMA bf16): [oself | h2] = h @ w2t^T. K=128, N=32, fp32 out.
// ---------------------------------------------------------------------------
__global__ __launch_bounds__(256) void gemm2_mfma_kernel(
    const uint* __restrict__ h, const uint* __restrict__ w2t,
    float* __restrict__ oself, float* __restrict__ h2) {
  int wid = (blockIdx.x * 256 + threadIdx.x) >> 6;
  int lane = threadIdx.x & 63;
  int r0 = wid * 32;
  if (r0 >= NN) return;
  int lr = lane & 15, lk = lane >> 4;

  f32x4 acc[2][2];
#pragma unroll
  for (int i = 0; i < 2; i++)
#pragma unroll
    for (int j = 0; j < 2; j++) acc[i][j] = (f32x4){0.f, 0.f, 0.f, 0.f};

#pragma unroll
  for (int ks = 0; ks < 4; ks++) {
    int ku = ks * 16;
    uint4 a0 = *(const uint4*)(h + (size_t)(r0 + lr) * 64 + ku + lk * 4);
    uint4 a1 = *(const uint4*)(h + (size_t)(r0 + 16 + lr) * 64 + ku + lk * 4);
#pragma unroll
    for (int ct = 0; ct < 2; ct++) {
      uint4 bu = *(const uint4*)(w2t + (size_t)(ct * 16 + lr) * 64 + ku + lk * 4);
      acc[0][ct] = mfma_bf16(a0, bu, acc[0][ct]);
      acc[1][ct] = mfma_bf16(a1, bu, acc[1][ct]);
    }
  }

#pragma unroll
  for (int rt = 0; rt < 2; rt++) {
#pragma unroll
    for (int r = 0; r < 4; r++) {
      int row = r0 + rt * 16 + lk * 4 + r;
      oself[(size_t)row * 16 + lr] = acc[rt][0][r];
      h2[(size_t)row * 16 + lr]    = acc[rt][1][r];
    }
  }
}

// ---------------------------------------------------------------------------
// Layer-2 mean aggregation + log_softmax epilogue (final fused in).
// One wave per node: lane q (0..15) owns feat q; 4 edge slots (lane>>4);
// reduce = 2 shfl_xor; then logits + 16-lane log_softmax; write out.
// ---------------------------------------------------------------------------
__global__ __launch_bounds__(256) void mean2_kernel(
    const float* __restrict__ h2, const int* __restrict__ off,
    const int* __restrict__ deg, const int* __restrict__ perm,
    const float* __restrict__ oself, const float* __restrict__ b2,
    float* __restrict__ out) {
  int node = blockIdx.x * 4 + (threadIdx.x >> 6);
  int lane = threadIdx.x & 63;
  if (node >= NN) return;
  int o = off[node], dg = deg[node];
  int slot = lane >> 4;   // 4 edge slots
  int q = lane & 15;      // owned feature
  float a = 0.f;
  int j = 0;
  for (; j + 8 <= dg; j += 8) {   // 2 loads in flight
    int sA = perm[o + j + slot];
    int sB = perm[o + j + 4 + slot];
    a += h2[(size_t)sA * 16 + q];
    a += h2[(size_t)sB * 16 + q];
  }
  for (; j + 4 <= dg; j += 4) {
    int s = perm[o + j + slot];
    a += h2[(size_t)s * 16 + q];
  }
  if (j < dg && j + slot < dg) {
    int s = perm[o + j + slot];
    a += h2[(size_t)s * 16 + q];
  }
  a += __shfl_xor(a, 16);
  a += __shfl_xor(a, 32);
  float rd = 1.0f / fmaxf((float)dg, 1.0f);
  float l = oself[(size_t)node * 16 + q] + b2[q] + a * rd;
  // log_softmax across the 16-lane feature group
  float m = l;
#pragma unroll
  for (int d = 1; d <= 8; d <<= 1) m = fmaxf(m, __shfl_xor(m, d));
  float ex = __expf(l - m);
  float s = ex;
#pragma unroll
  for (int d = 1; d <= 8; d <<= 1) s += __shfl_xor(s, d);
  if (lane < 16) out[(size_t)node * 16 + q] = l - m - logf(s);
}

// ---------------------------------------------------------------------------
extern "C" void kernel_launch(void* const* d_in, const int* in_sizes, int n_in,
                              void* d_out, int out_size, void* d_ws, size_t ws_size,
                              hipStream_t stream) {
  const float* x   = (const float*)d_in[0];
  const int*   src = (const int*)d_in[1];
  const int*   dst = (const int*)d_in[2];
  const float* ws1 = (const float*)d_in[3];
  const float* wn1 = (const float*)d_in[4];
  const float* b1  = (const float*)d_in[5];
  const float* ws2 = (const float*)d_in[6];
  const float* wn2 = (const float*)d_in[7];
  const float* b2  = (const float*)d_in[8];
  float* out = (float*)d_out;

  // workspace layout (xq aliases hbuf: xq dead before gemm1 writes hbuf)
  char* p = (char*)d_ws;
  int* deg   = (int*)p;  p += (size_t)NN * 4;
  int* off   = (int*)p;  p += (size_t)NN * 4;
  int* hist  = (int*)p;  p += (size_t)NH * 4;            // bucket-major, scanned in place
  int* hist2 = (int*)p;  p += (size_t)NH * 4;            // block-major
  int* sums  = (int*)p;  p += (size_t)((NSB + 31) & ~31) * 4;
  unsigned int* ebuf = (unsigned int*)p; p += (size_t)NE * 4;
  int* perm = (int*)p;  p += (size_t)NE * 4;
  uint* xh   = (uint*)p; p += (size_t)NN * 64 * 4;       // bf16 x, row-major
  uint* m1h  = (uint*)p; p += (size_t)NN * 64 * 4;       // bf16 mean1, row-major
  uint* hbuf = (uint*)p; p += (size_t)NN * 64 * 4;       // bf16 h (gemm1 out)
  uint* xq   = hbuf;                                     // fp8 x (12.8 MB), dead before hbuf written
  uint* w1t  = (uint*)p; p += (size_t)128 * 128 * 4;     // bf16 [ws1;wn1]^T
  uint* w2t  = (uint*)p; p += (size_t)32 * 64 * 4;       // bf16 [ws2|wn2]^T
  float* h2    = (float*)p; p += (size_t)NN * 16 * 4;
  float* osf   = (float*)p; p += (size_t)NN * 16 * 4;

  tobf16_kernel<<<(NN * 16 + 255) / 256, 256, 0, stream>>>(x, xh, xq);
  prep_w_kernel<<<(128 * 128 + 32 * 64 + 255) / 256, 256, 0, stream>>>(
      ws1, wn1, ws2, wn2, w1t, w2t);

  histA_kernel<<<NBLK, 1024, 0, stream>>>(dst, hist2);
  transpose_kernel<<<dim3((NBUCK + 31) / 32, NBLK / 32), 1024, 0, stream>>>(
      hist2, hist);
  scan_sums_kernel<<<NSB, 1024, 0, stream>>>(hist, sums);
  scan_tops_kernel<<<1, 512, 0, stream>>>(sums);
  scan_apply_kernel<<<NSB, 1024, 0, stream>>>(hist, sums);
  scatter3_kernel<<<NBLK, 1024, 0, stream>>>(src, dst, hist, ebuf);
  bucket_sort_kernel<<<NBUCK, 256, 0, stream>>>(ebuf, hist, deg, off, perm);

  mean1_kernel<<<(NN + 3) / 4, 256, 0, stream>>>(xq, off, deg, perm, m1h);

  gemm1_mfma_kernel<<<(NN + 255) / 256, 256, 0, stream>>>(
      xh, m1h, w1t, b1, (ushort_t*)hbuf);
  gemm2_mfma_kernel<<<(NN + 127) / 128, 256, 0, stream>>>(hbuf, w2t, osf, h2);

  mean2_kernel<<<(NN + 3) / 4, 256, 0, stream>>>(h2, off, deg, perm, osf, b2, out);
}

// Round 17
// 180.061 us; speedup vs baseline: 1.0681x; 1.0681x over previous
//
#include <hip/hip_runtime.h>
#include <math.h>

#define NN 100000
#define NE 1600000
#define BSZ 64                          // dst nodes per bucket
#define NBUCK ((NN + BSZ - 1) / BSZ)    // 1563
#define NBLK 256                        // scatter blocks / hist columns
#define CHUNK ((NE + NBLK - 1) / NBLK)  // 6250 edges per block
#define NH (NBUCK * NBLK)               // 400128 hist entries
#define NSB ((NH + 1023) / 1024)        // 391 scan blocks

typedef unsigned int uint;
typedef unsigned short ushort_t;
typedef float f32x2 __attribute__((ext_vector_type(2)));
typedef float f32x4 __attribute__((ext_vector_type(4)));
typedef short s16x8 __attribute__((ext_vector_type(8)));

union U4S8 { uint4 u; s16x8 s; };

// bf16 helpers (RNE pack)
__device__ inline uint bf16_1(float f) {
  uint u = __float_as_uint(f);
  return (u + 0x7FFFu + ((u >> 16) & 1u)) >> 16;
}
__device__ inline uint bf16_2(float lo, float hi) {
  return bf16_1(lo) | (bf16_1(hi) << 16);
}

__device__ inline f32x4 mfma_bf16(uint4 a, uint4 b, f32x4 c) {
  U4S8 ua, ub; ua.u = a; ub.u = b;
  return __builtin_amdgcn_mfma_f32_16x16x32_bf16(ua.s, ub.s, c, 0, 0, 0);
}

// ---------------------------------------------------------------------------
// x (fp32 [NN][128]) -> xh (bf16, [NN][64] uints) AND xq (fp8 e4m3,
// [NN][32] uints).
// ---------------------------------------------------------------------------
__global__ __launch_bounds__(256) void tobf16_kernel(
    const float* __restrict__ x, uint* __restrict__ xh,
    uint* __restrict__ xq) {
  int i = blockIdx.x * 256 + threadIdx.x;
  if (i >= NN * 16) return;
  const float4* p = (const float4*)x + (size_t)i * 2;
  float4 a = p[0], b = p[1];
  uint4 o;
  o.x = bf16_2(a.x, a.y);
  o.y = bf16_2(a.z, a.w);
  o.z = bf16_2(b.x, b.y);
  o.w = bf16_2(b.z, b.w);
  ((uint4*)xh)[i] = o;
  int q0 = __builtin_amdgcn_cvt_pk_fp8_f32(a.x, a.y, 0, false);
  q0 = __builtin_amdgcn_cvt_pk_fp8_f32(a.z, a.w, q0, true);
  int q1 = __builtin_amdgcn_cvt_pk_fp8_f32(b.x, b.y, 0, false);
  q1 = __builtin_amdgcn_cvt_pk_fp8_f32(b.z, b.w, q1, true);
  uint2 oq; oq.x = (uint)q0; oq.y = (uint)q1;
  int r = i >> 4;
  int u = (i & 15) * 2;
  *(uint2*)(xq + (size_t)r * 32 + u) = oq;
}

// ---------------------------------------------------------------------------
// Weight prep (fused): w1t (16384 entries) then w2t (2048 entries).
// ---------------------------------------------------------------------------
__global__ __launch_bounds__(256) void prep_w_kernel(
    const float* __restrict__ ws1, const float* __restrict__ wn1,
    const float* __restrict__ ws2, const float* __restrict__ wn2,
    uint* __restrict__ w1t, uint* __restrict__ w2t) {
  int idx = blockIdx.x * 256 + threadIdx.x;
  if (idx < 128 * 128) {
    int col = idx >> 7, ku = idx & 127;
    int k = ku * 2;
    const float* w = (k < 128) ? ws1 : wn1;
    int kk = (k < 128) ? k : (k - 128);
    w1t[idx] = bf16_2(w[(size_t)kk * 128 + col], w[(size_t)(kk + 1) * 128 + col]);
  } else if (idx < 128 * 128 + 32 * 64) {
    int j = idx - 128 * 128;
    int col = j >> 6, ku = j & 63;
    int k = ku * 2;
    const float* w = (col < 16) ? ws2 : wn2;
    int c = col & 15;
    w2t[j] = bf16_2(w[(size_t)k * 16 + c], w[(size_t)(k + 1) * 16 + c]);
  }
}

// ---------------------------------------------------------------------------
// Pass A: per-block bucket histogram, LDS atomics only, coalesced output.
// ---------------------------------------------------------------------------
__global__ __launch_bounds__(1024) void histA_kernel(
    const int* __restrict__ dst, int* __restrict__ hist2) {
  __shared__ int lh[NBUCK];
  int tid = threadIdx.x;
  int b = blockIdx.x;
  for (int i = tid; i < NBUCK; i += 1024) lh[i] = 0;
  __syncthreads();
  int e0 = b * CHUNK, e1 = min(e0 + CHUNK, NE);
  for (int e = e0 + tid; e < e1; e += 1024) {
    atomicAdd(&lh[dst[e] >> 6], 1);
  }
  __syncthreads();
  for (int i = tid; i < NBUCK; i += 1024)
    hist2[(size_t)b * NBUCK + i] = lh[i];
}

// ---------------------------------------------------------------------------
// Transpose hist2[NBLK][NBUCK] -> hist[NBUCK][NBLK].
// ---------------------------------------------------------------------------
__global__ __launch_bounds__(1024) void transpose_kernel(
    const int* __restrict__ hist2, int* __restrict__ hist) {
  __shared__ int t[32][33];
  int tx = threadIdx.x & 31, ty = threadIdx.x >> 5;
  int i = blockIdx.x * 32 + tx;
  int b = blockIdx.y * 32 + ty;
  if (i < NBUCK) t[ty][tx] = hist2[(size_t)b * NBUCK + i];
  __syncthreads();
  int i2 = blockIdx.x * 32 + ty;
  int b2 = blockIdx.y * 32 + tx;
  if (i2 < NBUCK) hist[(size_t)i2 * NBLK + b2] = t[tx][ty];
}

// ---------------------------------------------------------------------------
// Multi-block exclusive scan over hist[NH] (in-place), 3 kernels.
// ---------------------------------------------------------------------------
__global__ __launch_bounds__(1024) void scan_sums_kernel(
    const int* __restrict__ hist, int* __restrict__ sums) {
  __shared__ int sdata[1024];
  int i = blockIdx.x * 1024 + threadIdx.x;
  sdata[threadIdx.x] = (i < NH) ? hist[i] : 0;
  __syncthreads();
#pragma unroll
  for (int s = 512; s > 0; s >>= 1) {
    if (threadIdx.x < s) sdata[threadIdx.x] += sdata[threadIdx.x + s];
    __syncthreads();
  }
  if (threadIdx.x == 0) sums[blockIdx.x] = sdata[0];
}

__global__ __launch_bounds__(512) void scan_tops_kernel(int* __restrict__ sums) {
  __shared__ int buf[2][512];
  int tid = threadIdx.x;
  int v = (tid < NSB) ? sums[tid] : 0;
  buf[0][tid] = v;
  __syncthreads();
  int pp = 0;
#pragma unroll
  for (int d = 1; d < 512; d <<= 1) {
    buf[pp ^ 1][tid] = buf[pp][tid] + ((tid >= d) ? buf[pp][tid - d] : 0);
    pp ^= 1;
    __syncthreads();
  }
  if (tid < NSB) sums[tid] = buf[pp][tid] - v;  // exclusive
}

__global__ __launch_bounds__(1024) void scan_apply_kernel(
    int* __restrict__ hist, const int* __restrict__ sums) {
  __shared__ int buf[2][1024];
  int tid = threadIdx.x;
  int i = blockIdx.x * 1024 + tid;
  int v = (i < NH) ? hist[i] : 0;
  buf[0][tid] = v;
  __syncthreads();
  int pp = 0;
#pragma unroll
  for (int d = 1; d < 1024; d <<= 1) {
    buf[pp ^ 1][tid] = buf[pp][tid] + ((tid >= d) ? buf[pp][tid - d] : 0);
    pp ^= 1;
    __syncthreads();
  }
  if (i < NH) hist[i] = sums[blockIdx.x] + buf[pp][tid] - v;  // exclusive
}

// ---------------------------------------------------------------------------
// Pass C: contention-free scatter via scanned per-(bucket,block) cursors.
// ---------------------------------------------------------------------------
__global__ __launch_bounds__(1024) void scatter3_kernel(
    const int* __restrict__ src, const int* __restrict__ dst,
    const int* __restrict__ scanned, unsigned int* __restrict__ ebuf) {
  __shared__ int cur[NBUCK];
  int tid = threadIdx.x;
  int b = blockIdx.x;
  for (int i = tid; i < NBUCK; i += 1024) cur[i] = scanned[i * NBLK + b];
  __syncthreads();
  int e0 = b * CHUNK, e1 = min(e0 + CHUNK, NE);
  for (int e = e0 + tid; e < e1; e += 1024) {
    int d = dst[e];
    int p = atomicAdd(&cur[d >> 6], 1);
    ebuf[p] = ((unsigned int)(d & 63) << 17) | (unsigned int)src[e];
  }
}

// ---------------------------------------------------------------------------
// Per-bucket counting sort, two-pass (computes deg + off, no global atomics).
// ---------------------------------------------------------------------------
__global__ __launch_bounds__(256) void bucket_sort_kernel(
    const unsigned int* __restrict__ ebuf, const int* __restrict__ scanned,
    int* __restrict__ deg, int* __restrict__ off, int* __restrict__ perm) {
  __shared__ int cnt[BSZ];
  __shared__ int loc_off[BSZ];
  int tid = threadIdx.x;
  int b = blockIdx.x;
  int e0 = scanned[b * NBLK];
  int e1 = (b + 1 < NBUCK) ? scanned[(b + 1) * NBLK] : NE;

  if (tid < BSZ) cnt[tid] = 0;
  __syncthreads();
  for (int e = e0 + tid; e < e1; e += 256)
    atomicAdd(&cnt[ebuf[e] >> 17], 1);
  __syncthreads();

  if (tid < BSZ) {   // threads 0..63 = one wave
    int v = cnt[tid];
    int incl = v;
#pragma unroll
    for (int d = 1; d < 64; d <<= 1) {
      int t = __shfl_up(incl, d);
      if (tid >= d) incl += t;
    }
    int excl = incl - v;
    loc_off[tid] = e0 + excl;
    int node = b * BSZ + tid;
    if (node < NN) { off[node] = e0 + excl; deg[node] = v; }
    cnt[tid] = 0;
  }
  __syncthreads();

  for (int e = e0 + tid; e < e1; e += 256) {
    unsigned int pk = ebuf[e];
    int dl = pk >> 17;
    int p = loc_off[dl] + atomicAdd(&cnt[dl], 1);
    perm[p] = (int)(pk & 0x1FFFF);
  }
}

// ---------------------------------------------------------------------------
// Layer-1 mean aggregation (r15 form — measured floor): one wave per node.
// Lane q (0..31) owns fp8-uint q (feats 4q..4q+3); 2 edge slots (lane>>5),
// unroll x4 -> 4 row-loads in flight. 4 shfl per node. Coalesced write.
// ---------------------------------------------------------------------------
__global__ __launch_bounds__(256) void mean1_kernel(
    const uint* __restrict__ xq, const int* __restrict__ off,
    const int* __restrict__ deg, const int* __restrict__ perm,
    uint* __restrict__ m1h) {
  int node = blockIdx.x * 4 + (threadIdx.x >> 6);
  int lane = threadIdx.x & 63;
  if (node >= NN) return;
  int o = off[node], dg = deg[node];
  int slot = lane >> 5;   // 0 or 1
  int q = lane & 31;      // uint within the 32-uint fp8 row
  f32x2 a0 = {0.f, 0.f}, a1 = {0.f, 0.f};
  int j = 0;
  for (; j + 8 <= dg; j += 8) {   // slot s handles j+s, j+2+s, j+4+s, j+6+s
    int sA = perm[o + j + slot];
    int sB = perm[o + j + 2 + slot];
    int sC = perm[o + j + 4 + slot];
    int sD = perm[o + j + 6 + slot];
    uint vA = xq[(size_t)sA * 32 + q];
    uint vB = xq[(size_t)sB * 32 + q];
    uint vC = xq[(size_t)sC * 32 + q];
    uint vD = xq[(size_t)sD * 32 + q];
    a0 += __builtin_amdgcn_cvt_pk_f32_fp8(vA, 0);
    a1 += __builtin_amdgcn_cvt_pk_f32_fp8(vA, 1);
    a0 += __builtin_amdgcn_cvt_pk_f32_fp8(vB, 0);
    a1 += __builtin_amdgcn_cvt_pk_f32_fp8(vB, 1);
    a0 += __builtin_amdgcn_cvt_pk_f32_fp8(vC, 0);
    a1 += __builtin_amdgcn_cvt_pk_f32_fp8(vC, 1);
    a0 += __builtin_amdgcn_cvt_pk_f32_fp8(vD, 0);
    a1 += __builtin_amdgcn_cvt_pk_f32_fp8(vD, 1);
  }
  for (; j + 2 <= dg; j += 2) {
    int s = perm[o + j + slot];
    uint v = xq[(size_t)s * 32 + q];
    a0 += __builtin_amdgcn_cvt_pk_f32_fp8(v, 0);
    a1 += __builtin_amdgcn_cvt_pk_f32_fp8(v, 1);
  }
  if (j < dg && slot == 0) {   // odd last edge
    int s = perm[o + j];
    uint v = xq[(size_t)s * 32 + q];
    a0 += __builtin_amdgcn_cvt_pk_f32_fp8(v, 0);
    a1 += __builtin_amdgcn_cvt_pk_f32_fp8(v, 1);
  }
  a0.x += __shfl_xor(a0.x, 32);
  a0.y += __shfl_xor(a0.y, 32);
  a1.x += __shfl_xor(a1.x, 32);
  a1.y += __shfl_xor(a1.y, 32);
  if (slot == 0) {
    float rd = 1.0f / fmaxf((float)dg, 1.0f);
    uint2 o2;
    o2.x = bf16_2(a0.x * rd, a0.y * rd);
    o2.y = bf16_2(a1.x * rd, a1.y * rd);
    *(uint2*)(m1h + (size_t)node * 64 + q * 2) = o2;
  }
}

// ---------------------------------------------------------------------------
// FUSED GEMM1+GEMM2 (MFMA bf16):
//   h = relu([xh | m1h] @ w1t^T + b1)   (kept in LDS, never hits HBM)
//   [oself | h2] = h @ w2t^T
// Phase 1: stage w1t (64 KB, XOR-swizzled) -> LDS; per-wave 64-row MFMA.
// Phase 2: barrier; overwrite LDS with the block's h-tile (bf16 ushort,
// chunk-XOR swizzle cs = chunk ^ ((row&7)<<1), 2-way-free banks both ways);
// each wave reads back only its own quarter -> K=128/N=32 MFMA -> osf/h2.
// ---------------------------------------------------------------------------
__global__ __launch_bounds__(256) void gemm12_kernel(
    const uint* __restrict__ xh, const uint* __restrict__ m1h,
    const uint* __restrict__ w1t, const uint* __restrict__ w2t,
    const float* __restrict__ b1, float* __restrict__ oself,
    float* __restrict__ h2) {
  __shared__ uint lds_w[128 * 128];   // 64 KB; reused as ushort h-tile
  int tid = threadIdx.x;

#pragma unroll
  for (int i = 0; i < 16; i++) {
    int g = tid + i * 256;
    int row = g >> 5, c = g & 31;
    uint4 v = ((const uint4*)w1t)[g];
    int cs = c ^ (row & 7);
    *(uint4*)&lds_w[row * 128 + cs * 4] = v;
  }
  __syncthreads();

  int wv = tid >> 6;
  int lane = tid & 63;
  int lr = lane & 15, lk = lane >> 4;
  int r0 = blockIdx.x * 256 + wv * 64;   // may exceed NN for tail waves

  f32x4 acc[4][8];
#pragma unroll
  for (int i = 0; i < 4; i++)
#pragma unroll
    for (int j = 0; j < 8; j++) acc[i][j] = (f32x4){0.f, 0.f, 0.f, 0.f};

#pragma unroll
  for (int ks = 0; ks < 8; ks++) {
    const uint* A = (ks < 4) ? xh : m1h;
    int ku = (ks & 3) * 16 + lk * 4;
    uint4 a[4];
#pragma unroll
    for (int rt = 0; rt < 4; rt++) {
      int row = r0 + rt * 16 + lr;
      if (row >= NN) row = NN - 1;
      a[rt] = *(const uint4*)(A + (size_t)row * 64 + ku);
    }
    int cbase = ks * 4 + lk;
#pragma unroll
    for (int ct = 0; ct < 8; ct++) {
      int brow = ct * 16 + lr;
      int cs = cbase ^ (lr & 7);
      uint4 bu = *(const uint4*)&lds_w[brow * 128 + cs * 4];
#pragma unroll
      for (int rt = 0; rt < 4; rt++)
        acc[rt][ct] = mfma_bf16(a[rt], bu, acc[rt][ct]);
    }
  }

  float bias[8];
#pragma unroll
  for (int ct = 0; ct < 8; ct++) bias[ct] = b1[ct * 16 + lr];

  __syncthreads();   // all w1t reads done; LDS can be overwritten

  // Phase 2a: write h-tile (bf16) into LDS, swizzled. Wave's own quarter.
  ushort_t* lds_h = (ushort_t*)lds_w;
#pragma unroll
  for (int rt = 0; rt < 4; rt++) {
#pragma unroll
    for (int r = 0; r < 4; r++) {
      int rel = wv * 64 + rt * 16 + lk * 4 + r;   // row within block tile
#pragma unroll
      for (int ct = 0; ct < 8; ct++) {
        int col = ct * 16 + lr;
        float v = fmaxf(acc[rt][ct][r] + bias[ct], 0.0f);
        int chunk = col >> 3;
        int cs = chunk ^ ((rel & 7) << 1);
        lds_h[rel * 128 + (cs << 3) + (col & 7)] = (ushort_t)bf16_1(v);
      }
    }
  }
  // no barrier: each wave reads only its own quarter

  // Phase 2b: gemm2 from LDS h-tile. 64 rows x 32 cols per wave.
  f32x4 acc2[4][2];
#pragma unroll
  for (int i = 0; i < 4; i++)
#pragma unroll
    for (int j = 0; j < 2; j++) acc2[i][j] = (f32x4){0.f, 0.f, 0.f, 0.f};

#pragma unroll
  for (int ks = 0; ks < 4; ks++) {
    uint4 a[4];
#pragma unroll
    for (int rt = 0; rt < 4; rt++) {
      int rel = wv * 64 + rt * 16 + lr;
      int chunk = ks * 4 + lk;
      int cs = chunk ^ ((rel & 7) << 1);
      a[rt] = *(const uint4*)&lds_h[rel * 128 + (cs << 3)];
    }
#pragma unroll
    for (int ct = 0; ct < 2; ct++) {
      uint4 bu = *(const uint4*)(w2t + (size_t)(ct * 16 + lr) * 64 + ks * 16 + lk * 4);
      acc2[0][ct] = mfma_bf16(a[0], bu, acc2[0][ct]);
      acc2[1][ct] = mfma_bf16(a[1], bu, acc2[1][ct]);
      acc2[2][ct] = mfma_bf16(a[2], bu, acc2[2][ct]);
      acc2[3][ct] = mfma_bf16(a[3], bu, acc2[3][ct]);
    }
  }

#pragma unroll
  for (int rt = 0; rt < 4; rt++) {
#pragma unroll
    for (int r = 0; r < 4; r++) {
      int row = r0 + rt * 16 + lk * 4 + r;
      if (row < NN) {
        oself[(size_t)row * 16 + lr] = acc2[rt][0][r];
        h2[(size_t)row * 16 + lr]    = acc2[rt][1][r];
      }
    }
  }
}

// ---------------------------------------------------------------------------
// Layer-2 mean aggregation + log_softmax epilogue.
// One wave per node: lane q (0..15) owns feat q; 4 edge slots (lane>>4);
// reduce = 2 shfl_xor; then logits + 16-lane log_softmax; write out.
// ---------------------------------------------------------------------------
__global__ __launch_bounds__(256) void mean2_kernel(
    const float* __restrict__ h2, const int* __restrict__ off,
    const int* __restrict__ deg, const int* __restrict__ perm,
    const float* __restrict__ oself, const float* __restrict__ b2,
    float* __restrict__ out) {
  int node = blockIdx.x * 4 + (threadIdx.x >> 6);
  int lane = threadIdx.x & 63;
  if (node >= NN) return;
  int o = off[node], dg = deg[node];
  int slot = lane >> 4;   // 4 edge slots
  int q = lane & 15;      // owned feature
  float a = 0.f;
  int j = 0;
  for (; j + 8 <= dg; j += 8) {   // 2 loads in flight
    int sA = perm[o + j + slot];
    int sB = perm[o + j + 4 + slot];
    a += h2[(size_t)sA * 16 + q];
    a += h2[(size_t)sB * 16 + q];
  }
  for (; j + 4 <= dg; j += 4) {
    int s = perm[o + j + slot];
    a += h2[(size_t)s * 16 + q];
  }
  if (j < dg && j + slot < dg) {
    int s = perm[o + j + slot];
    a += h2[(size_t)s * 16 + q];
  }
  a += __shfl_xor(a, 16);
  a += __shfl_xor(a, 32);
  float rd = 1.0f / fmaxf((float)dg, 1.0f);
  float l = oself[(size_t)node * 16 + q] + b2[q] + a * rd;
  float m = l;
#pragma unroll
  for (int d = 1; d <= 8; d <<= 1) m = fmaxf(m, __shfl_xor(m, d));
  float ex = __expf(l - m);
  float s = ex;
#pragma unroll
  for (int d = 1; d <= 8; d <<= 1) s += __shfl_xor(s, d);
  if (lane < 16) out[(size_t)node * 16 + q] = l - m - logf(s);
}

// ---------------------------------------------------------------------------
extern "C" void kernel_launch(void* const* d_in, const int* in_sizes, int n_in,
                              void* d_out, int out_size, void* d_ws, size_t ws_size,
                              hipStream_t stream) {
  const float* x   = (const float*)d_in[0];
  const int*   src = (const int*)d_in[1];
  const int*   dst = (const int*)d_in[2];
  const float* ws1 = (const float*)d_in[3];
  const float* wn1 = (const float*)d_in[4];
  const float* b1  = (const float*)d_in[5];
  const float* ws2 = (const float*)d_in[6];
  const float* wn2 = (const float*)d_in[7];
  const float* b2  = (const float*)d_in[8];
  float* out = (float*)d_out;

  // workspace layout
  char* p = (char*)d_ws;
  int* deg   = (int*)p;  p += (size_t)NN * 4;
  int* off   = (int*)p;  p += (size_t)NN * 4;
  int* hist  = (int*)p;  p += (size_t)NH * 4;            // bucket-major, scanned in place
  int* hist2 = (int*)p;  p += (size_t)NH * 4;            // block-major
  int* sums  = (int*)p;  p += (size_t)((NSB + 31) & ~31) * 4;
  unsigned int* ebuf = (unsigned int*)p; p += (size_t)NE * 4;
  int* perm = (int*)p;  p += (size_t)NE * 4;
  uint* xh   = (uint*)p; p += (size_t)NN * 64 * 4;       // bf16 x, row-major
  uint* m1h  = (uint*)p; p += (size_t)NN * 64 * 4;       // bf16 mean1, row-major
  uint* xq   = (uint*)p; p += (size_t)NN * 32 * 4;       // fp8 x (12.8 MB)
  uint* w1t  = (uint*)p; p += (size_t)128 * 128 * 4;     // bf16 [ws1;wn1]^T
  uint* w2t  = (uint*)p; p += (size_t)32 * 64 * 4;       // bf16 [ws2|wn2]^T
  float* h2    = (float*)p; p += (size_t)NN * 16 * 4;
  float* osf   = (float*)p; p += (size_t)NN * 16 * 4;

  tobf16_kernel<<<(NN * 16 + 255) / 256, 256, 0, stream>>>(x, xh, xq);
  prep_w_kernel<<<(128 * 128 + 32 * 64 + 255) / 256, 256, 0, stream>>>(
      ws1, wn1, ws2, wn2, w1t, w2t);

  histA_kernel<<<NBLK, 1024, 0, stream>>>(dst, hist2);
  transpose_kernel<<<dim3((NBUCK + 31) / 32, NBLK / 32), 1024, 0, stream>>>(
      hist2, hist);
  scan_sums_kernel<<<NSB, 1024, 0, stream>>>(hist, sums);
  scan_tops_kernel<<<1, 512, 0, stream>>>(sums);
  scan_apply_kernel<<<NSB, 1024, 0, stream>>>(hist, sums);
  scatter3_kernel<<<NBLK, 1024, 0, stream>>>(src, dst, hist, ebuf);
  bucket_sort_kernel<<<NBUCK, 256, 0, stream>>>(ebuf, hist, deg, off, perm);

  mean1_kernel<<<(NN + 3) / 4, 256, 0, stream>>>(xq, off, deg, perm, m1h);

  gemm12_kernel<<<(NN + 255) / 256, 256, 0, stream>>>(
      xh, m1h, w1t, w2t, b1, osf, h2);

  mean2_kernel<<<(NN + 3) / 4, 256, 0, stream>>>(h2, off, deg, perm, osf, b2, out);
}

// Round 18
// 170.059 us; speedup vs baseline: 1.1310x; 1.0588x over previous
//
#include <hip/hip_runtime.h>
#include <math.h>

#define NN 100000
#define NE 1600000
#define BSZ 64                          // dst nodes per bucket
#define NBUCK ((NN + BSZ - 1) / BSZ)    // 1563
#define NBLK 256                        // scatter blocks / hist columns
#define CHUNK ((NE + NBLK - 1) / NBLK)  // 6250 edges per block
#define NH (NBUCK * NBLK)               // 400128 hist entries
#define NSB ((NH + 1023) / 1024)        // 391 scan blocks

typedef unsigned int uint;
typedef unsigned short ushort_t;
typedef float f32x2 __attribute__((ext_vector_type(2)));
typedef float f32x4 __attribute__((ext_vector_type(4)));
typedef short s16x8 __attribute__((ext_vector_type(8)));

union U4S8 { uint4 u; s16x8 s; };

// bf16 helpers (RNE pack, shift decode)
__device__ inline uint bf16_1(float f) {
  uint u = __float_as_uint(f);
  return (u + 0x7FFFu + ((u >> 16) & 1u)) >> 16;
}
__device__ inline uint bf16_2(float lo, float hi) {
  return bf16_1(lo) | (bf16_1(hi) << 16);
}
__device__ inline float blo(uint u) { return __uint_as_float(u << 16); }
__device__ inline float bhi(uint u) { return __uint_as_float(u & 0xFFFF0000u); }

__device__ inline f32x4 mfma_bf16(uint4 a, uint4 b, f32x4 c) {
  U4S8 ua, ub; ua.u = a; ub.u = b;
  return __builtin_amdgcn_mfma_f32_16x16x32_bf16(ua.s, ub.s, c, 0, 0, 0);
}

// ---------------------------------------------------------------------------
// x (fp32 [NN][128]) -> xh (bf16, [NN][64] uints) AND xq (fp8 e4m3,
// [NN][32] uints).
// ---------------------------------------------------------------------------
__global__ __launch_bounds__(256) void tobf16_kernel(
    const float* __restrict__ x, uint* __restrict__ xh,
    uint* __restrict__ xq) {
  int i = blockIdx.x * 256 + threadIdx.x;
  if (i >= NN * 16) return;
  const float4* p = (const float4*)x + (size_t)i * 2;
  float4 a = p[0], b = p[1];
  uint4 o;
  o.x = bf16_2(a.x, a.y);
  o.y = bf16_2(a.z, a.w);
  o.z = bf16_2(b.x, b.y);
  o.w = bf16_2(b.z, b.w);
  ((uint4*)xh)[i] = o;
  int q0 = __builtin_amdgcn_cvt_pk_fp8_f32(a.x, a.y, 0, false);
  q0 = __builtin_amdgcn_cvt_pk_fp8_f32(a.z, a.w, q0, true);
  int q1 = __builtin_amdgcn_cvt_pk_fp8_f32(b.x, b.y, 0, false);
  q1 = __builtin_amdgcn_cvt_pk_fp8_f32(b.z, b.w, q1, true);
  uint2 oq; oq.x = (uint)q0; oq.y = (uint)q1;
  int r = i >> 4;
  int u = (i & 15) * 2;
  *(uint2*)(xq + (size_t)r * 32 + u) = oq;
}

// ---------------------------------------------------------------------------
// Weight prep (fused): w1t (16384 entries) then w2t (2048 entries).
// ---------------------------------------------------------------------------
__global__ __launch_bounds__(256) void prep_w_kernel(
    const float* __restrict__ ws1, const float* __restrict__ wn1,
    const float* __restrict__ ws2, const float* __restrict__ wn2,
    uint* __restrict__ w1t, uint* __restrict__ w2t) {
  int idx = blockIdx.x * 256 + threadIdx.x;
  if (idx < 128 * 128) {
    int col = idx >> 7, ku = idx & 127;
    int k = ku * 2;
    const float* w = (k < 128) ? ws1 : wn1;
    int kk = (k < 128) ? k : (k - 128);
    w1t[idx] = bf16_2(w[(size_t)kk * 128 + col], w[(size_t)(kk + 1) * 128 + col]);
  } else if (idx < 128 * 128 + 32 * 64) {
    int j = idx - 128 * 128;
    int col = j >> 6, ku = j & 63;
    int k = ku * 2;
    const float* w = (col < 16) ? ws2 : wn2;
    int c = col & 15;
    w2t[j] = bf16_2(w[(size_t)k * 16 + c], w[(size_t)(k + 1) * 16 + c]);
  }
}

// ---------------------------------------------------------------------------
// Pass A: per-block bucket histogram, LDS atomics only, coalesced output.
// ---------------------------------------------------------------------------
__global__ __launch_bounds__(1024) void histA_kernel(
    const int* __restrict__ dst, int* __restrict__ hist2) {
  __shared__ int lh[NBUCK];
  int tid = threadIdx.x;
  int b = blockIdx.x;
  for (int i = tid; i < NBUCK; i += 1024) lh[i] = 0;
  __syncthreads();
  int e0 = b * CHUNK, e1 = min(e0 + CHUNK, NE);
  for (int e = e0 + tid; e < e1; e += 1024) {
    atomicAdd(&lh[dst[e] >> 6], 1);
  }
  __syncthreads();
  for (int i = tid; i < NBUCK; i += 1024)
    hist2[(size_t)b * NBUCK + i] = lh[i];
}

// ---------------------------------------------------------------------------
// Transpose hist2[NBLK][NBUCK] -> hist[NBUCK][NBLK].
// ---------------------------------------------------------------------------
__global__ __launch_bounds__(1024) void transpose_kernel(
    const int* __restrict__ hist2, int* __restrict__ hist) {
  __shared__ int t[32][33];
  int tx = threadIdx.x & 31, ty = threadIdx.x >> 5;
  int i = blockIdx.x * 32 + tx;
  int b = blockIdx.y * 32 + ty;
  if (i < NBUCK) t[ty][tx] = hist2[(size_t)b * NBUCK + i];
  __syncthreads();
  int i2 = blockIdx.x * 32 + ty;
  int b2 = blockIdx.y * 32 + tx;
  if (i2 < NBUCK) hist[(size_t)i2 * NBLK + b2] = t[tx][ty];
}

// ---------------------------------------------------------------------------
// Multi-block exclusive scan over hist[NH] (in-place), 3 kernels.
// ---------------------------------------------------------------------------
__global__ __launch_bounds__(1024) void scan_sums_kernel(
    const int* __restrict__ hist, int* __restrict__ sums) {
  __shared__ int sdata[1024];
  int i = blockIdx.x * 1024 + threadIdx.x;
  sdata[threadIdx.x] = (i < NH) ? hist[i] : 0;
  __syncthreads();
#pragma unroll
  for (int s = 512; s > 0; s >>= 1) {
    if (threadIdx.x < s) sdata[threadIdx.x] += sdata[threadIdx.x + s];
    __syncthreads();
  }
  if (threadIdx.x == 0) sums[blockIdx.x] = sdata[0];
}

__global__ __launch_bounds__(512) void scan_tops_kernel(int* __restrict__ sums) {
  __shared__ int buf[2][512];
  int tid = threadIdx.x;
  int v = (tid < NSB) ? sums[tid] : 0;
  buf[0][tid] = v;
  __syncthreads();
  int pp = 0;
#pragma unroll
  for (int d = 1; d < 512; d <<= 1) {
    buf[pp ^ 1][tid] = buf[pp][tid] + ((tid >= d) ? buf[pp][tid - d] : 0);
    pp ^= 1;
    __syncthreads();
  }
  if (tid < NSB) sums[tid] = buf[pp][tid] - v;  // exclusive
}

__global__ __launch_bounds__(1024) void scan_apply_kernel(
    int* __restrict__ hist, const int* __restrict__ sums) {
  __shared__ int buf[2][1024];
  int tid = threadIdx.x;
  int i = blockIdx.x * 1024 + tid;
  int v = (i < NH) ? hist[i] : 0;
  buf[0][tid] = v;
  __syncthreads();
  int pp = 0;
#pragma unroll
  for (int d = 1; d < 1024; d <<= 1) {
    buf[pp ^ 1][tid] = buf[pp][tid] + ((tid >= d) ? buf[pp][tid - d] : 0);
    pp ^= 1;
    __syncthreads();
  }
  if (i < NH) hist[i] = sums[blockIdx.x] + buf[pp][tid] - v;  // exclusive
}

// ---------------------------------------------------------------------------
// Pass C: contention-free scatter via scanned per-(bucket,block) cursors.
// ---------------------------------------------------------------------------
__global__ __launch_bounds__(1024) void scatter3_kernel(
    const int* __restrict__ src, const int* __restrict__ dst,
    const int* __restrict__ scanned, unsigned int* __restrict__ ebuf) {
  __shared__ int cur[NBUCK];
  int tid = threadIdx.x;
  int b = blockIdx.x;
  for (int i = tid; i < NBUCK; i += 1024) cur[i] = scanned[i * NBLK + b];
  __syncthreads();
  int e0 = b * CHUNK, e1 = min(e0 + CHUNK, NE);
  for (int e = e0 + tid; e < e1; e += 1024) {
    int d = dst[e];
    int p = atomicAdd(&cur[d >> 6], 1);
    ebuf[p] = ((unsigned int)(d & 63) << 17) | (unsigned int)src[e];
  }
}

// ---------------------------------------------------------------------------
// Per-bucket counting sort, two-pass (computes deg + off, no global atomics).
// ---------------------------------------------------------------------------
__global__ __launch_bounds__(256) void bucket_sort_kernel(
    const unsigned int* __restrict__ ebuf, const int* __restrict__ scanned,
    int* __restrict__ deg, int* __restrict__ off, int* __restrict__ perm) {
  __shared__ int cnt[BSZ];
  __shared__ int loc_off[BSZ];
  int tid = threadIdx.x;
  int b = blockIdx.x;
  int e0 = scanned[b * NBLK];
  int e1 = (b + 1 < NBUCK) ? scanned[(b + 1) * NBLK] : NE;

  if (tid < BSZ) cnt[tid] = 0;
  __syncthreads();
  for (int e = e0 + tid; e < e1; e += 256)
    atomicAdd(&cnt[ebuf[e] >> 17], 1);
  __syncthreads();

  if (tid < BSZ) {   // threads 0..63 = one wave
    int v = cnt[tid];
    int incl = v;
#pragma unroll
    for (int d = 1; d < 64; d <<= 1) {
      int t = __shfl_up(incl, d);
      if (tid >= d) incl += t;
    }
    int excl = incl - v;
    loc_off[tid] = e0 + excl;
    int node = b * BSZ + tid;
    if (node < NN) { off[node] = e0 + excl; deg[node] = v; }
    cnt[tid] = 0;
  }
  __syncthreads();

  for (int e = e0 + tid; e < e1; e += 256) {
    unsigned int pk = ebuf[e];
    int dl = pk >> 17;
    int p = loc_off[dl] + atomicAdd(&cnt[dl], 1);
    perm[p] = (int)(pk & 0x1FFFF);
  }
}

// ---------------------------------------------------------------------------
// Layer-1 mean aggregation (measured floor form): one wave per node.
// Lane q (0..31) owns fp8-uint q (feats 4q..4q+3); 2 edge slots (lane>>5),
// unroll x4 -> 4 row-loads in flight. 4 shfl per node. Coalesced write.
// ---------------------------------------------------------------------------
__global__ __launch_bounds__(256) void mean1_kernel(
    const uint* __restrict__ xq, const int* __restrict__ off,
    const int* __restrict__ deg, const int* __restrict__ perm,
    uint* __restrict__ m1h) {
  int node = blockIdx.x * 4 + (threadIdx.x >> 6);
  int lane = threadIdx.x & 63;
  if (node >= NN) return;
  int o = off[node], dg = deg[node];
  int slot = lane >> 5;   // 0 or 1
  int q = lane & 31;      // uint within the 32-uint fp8 row
  f32x2 a0 = {0.f, 0.f}, a1 = {0.f, 0.f};
  int j = 0;
  for (; j + 8 <= dg; j += 8) {
    int sA = perm[o + j + slot];
    int sB = perm[o + j + 2 + slot];
    int sC = perm[o + j + 4 + slot];
    int sD = perm[o + j + 6 + slot];
    uint vA = xq[(size_t)sA * 32 + q];
    uint vB = xq[(size_t)sB * 32 + q];
    uint vC = xq[(size_t)sC * 32 + q];
    uint vD = xq[(size_t)sD * 32 + q];
    a0 += __builtin_amdgcn_cvt_pk_f32_fp8(vA, 0);
    a1 += __builtin_amdgcn_cvt_pk_f32_fp8(vA, 1);
    a0 += __builtin_amdgcn_cvt_pk_f32_fp8(vB, 0);
    a1 += __builtin_amdgcn_cvt_pk_f32_fp8(vB, 1);
    a0 += __builtin_amdgcn_cvt_pk_f32_fp8(vC, 0);
    a1 += __builtin_amdgcn_cvt_pk_f32_fp8(vC, 1);
    a0 += __builtin_amdgcn_cvt_pk_f32_fp8(vD, 0);
    a1 += __builtin_amdgcn_cvt_pk_f32_fp8(vD, 1);
  }
  for (; j + 2 <= dg; j += 2) {
    int s = perm[o + j + slot];
    uint v = xq[(size_t)s * 32 + q];
    a0 += __builtin_amdgcn_cvt_pk_f32_fp8(v, 0);
    a1 += __builtin_amdgcn_cvt_pk_f32_fp8(v, 1);
  }
  if (j < dg && slot == 0) {
    int s = perm[o + j];
    uint v = xq[(size_t)s * 32 + q];
    a0 += __builtin_amdgcn_cvt_pk_f32_fp8(v, 0);
    a1 += __builtin_amdgcn_cvt_pk_f32_fp8(v, 1);
  }
  a0.x += __shfl_xor(a0.x, 32);
  a0.y += __shfl_xor(a0.y, 32);
  a1.x += __shfl_xor(a1.x, 32);
  a1.y += __shfl_xor(a1.y, 32);
  if (slot == 0) {
    float rd = 1.0f / fmaxf((float)dg, 1.0f);
    uint2 o2;
    o2.x = bf16_2(a0.x * rd, a0.y * rd);
    o2.y = bf16_2(a1.x * rd, a1.y * rd);
    *(uint2*)(m1h + (size_t)node * 64 + q * 2) = o2;
  }
}

// ---------------------------------------------------------------------------
// FUSED GEMM1+GEMM2 (MFMA bf16); h2 output now bf16 (3.2 MB -> per-XCD
// L2-resident for mean2's gather).
// ---------------------------------------------------------------------------
__global__ __launch_bounds__(256) void gemm12_kernel(
    const uint* __restrict__ xh, const uint* __restrict__ m1h,
    const uint* __restrict__ w1t, const uint* __restrict__ w2t,
    const float* __restrict__ b1, float* __restrict__ oself,
    ushort_t* __restrict__ h2b) {
  __shared__ uint lds_w[128 * 128];   // 64 KB; reused as ushort h-tile
  int tid = threadIdx.x;

#pragma unroll
  for (int i = 0; i < 16; i++) {
    int g = tid + i * 256;
    int row = g >> 5, c = g & 31;
    uint4 v = ((const uint4*)w1t)[g];
    int cs = c ^ (row & 7);
    *(uint4*)&lds_w[row * 128 + cs * 4] = v;
  }
  __syncthreads();

  int wv = tid >> 6;
  int lane = tid & 63;
  int lr = lane & 15, lk = lane >> 4;
  int r0 = blockIdx.x * 256 + wv * 64;

  f32x4 acc[4][8];
#pragma unroll
  for (int i = 0; i < 4; i++)
#pragma unroll
    for (int j = 0; j < 8; j++) acc[i][j] = (f32x4){0.f, 0.f, 0.f, 0.f};

#pragma unroll
  for (int ks = 0; ks < 8; ks++) {
    const uint* A = (ks < 4) ? xh : m1h;
    int ku = (ks & 3) * 16 + lk * 4;
    uint4 a[4];
#pragma unroll
    for (int rt = 0; rt < 4; rt++) {
      int row = r0 + rt * 16 + lr;
      if (row >= NN) row = NN - 1;
      a[rt] = *(const uint4*)(A + (size_t)row * 64 + ku);
    }
    int cbase = ks * 4 + lk;
#pragma unroll
    for (int ct = 0; ct < 8; ct++) {
      int brow = ct * 16 + lr;
      int cs = cbase ^ (lr & 7);
      uint4 bu = *(const uint4*)&lds_w[brow * 128 + cs * 4];
#pragma unroll
      for (int rt = 0; rt < 4; rt++)
        acc[rt][ct] = mfma_bf16(a[rt], bu, acc[rt][ct]);
    }
  }

  float bias[8];
#pragma unroll
  for (int ct = 0; ct < 8; ct++) bias[ct] = b1[ct * 16 + lr];

  __syncthreads();   // all w1t reads done; LDS can be overwritten

  // Phase 2a: write h-tile (bf16) into LDS, swizzled. Wave's own quarter.
  ushort_t* lds_h = (ushort_t*)lds_w;
#pragma unroll
  for (int rt = 0; rt < 4; rt++) {
#pragma unroll
    for (int r = 0; r < 4; r++) {
      int rel = wv * 64 + rt * 16 + lk * 4 + r;
#pragma unroll
      for (int ct = 0; ct < 8; ct++) {
        int col = ct * 16 + lr;
        float v = fmaxf(acc[rt][ct][r] + bias[ct], 0.0f);
        int chunk = col >> 3;
        int cs = chunk ^ ((rel & 7) << 1);
        lds_h[rel * 128 + (cs << 3) + (col & 7)] = (ushort_t)bf16_1(v);
      }
    }
  }
  // no barrier: each wave reads only its own quarter

  // Phase 2b: gemm2 from LDS h-tile. 64 rows x 32 cols per wave.
  f32x4 acc2[4][2];
#pragma unroll
  for (int i = 0; i < 4; i++)
#pragma unroll
    for (int j = 0; j < 2; j++) acc2[i][j] = (f32x4){0.f, 0.f, 0.f, 0.f};

#pragma unroll
  for (int ks = 0; ks < 4; ks++) {
    uint4 a[4];
#pragma unroll
    for (int rt = 0; rt < 4; rt++) {
      int rel = wv * 64 + rt * 16 + lr;
      int chunk = ks * 4 + lk;
      int cs = chunk ^ ((rel & 7) << 1);
      a[rt] = *(const uint4*)&lds_h[rel * 128 + (cs << 3)];
    }
#pragma unroll
    for (int ct = 0; ct < 2; ct++) {
      uint4 bu = *(const uint4*)(w2t + (size_t)(ct * 16 + lr) * 64 + ks * 16 + lk * 4);
      acc2[0][ct] = mfma_bf16(a[0], bu, acc2[0][ct]);
      acc2[1][ct] = mfma_bf16(a[1], bu, acc2[1][ct]);
      acc2[2][ct] = mfma_bf16(a[2], bu, acc2[2][ct]);
      acc2[3][ct] = mfma_bf16(a[3], bu, acc2[3][ct]);
    }
  }

#pragma unroll
  for (int rt = 0; rt < 4; rt++) {
#pragma unroll
    for (int r = 0; r < 4; r++) {
      int row = r0 + rt * 16 + lk * 4 + r;
      if (row < NN) {
        oself[(size_t)row * 16 + lr] = acc2[rt][0][r];
        h2b[(size_t)row * 16 + lr]  = (ushort_t)bf16_1(acc2[rt][1][r]);
      }
    }
  }
}

// ---------------------------------------------------------------------------
// Layer-2 mean aggregation from bf16 rows (32B, L2-resident) + log_softmax.
// One wave per node: lane q (0..7) owns uint q (feats 2q,2q+1);
// 8 edge slots (lane>>3), unroll x2 -> 16 edges in flight.
// Reduce = 3 shfl levels; 16-feat log_softmax across 8 lanes.
// ---------------------------------------------------------------------------
__global__ __launch_bounds__(256) void mean2_kernel(
    const ushort_t* __restrict__ h2b, const int* __restrict__ off,
    const int* __restrict__ deg, const int* __restrict__ perm,
    const float* __restrict__ oself, const float* __restrict__ b2,
    float* __restrict__ out) {
  int node = blockIdx.x * 4 + (threadIdx.x >> 6);
  int lane = threadIdx.x & 63;
  if (node >= NN) return;
  int o = off[node], dg = deg[node];
  int slot = lane >> 3;   // 8 edge slots
  int q = lane & 7;       // owned uint (feats 2q, 2q+1)
  const uint* hb = (const uint*)h2b;
  float a0 = 0.f, a1 = 0.f;
  int j = slot;
  for (; j + 8 < dg; j += 16) {   // 2 loads in flight
    int sA = perm[o + j];
    int sB = perm[o + j + 8];
    uint vA = hb[(size_t)sA * 8 + q];
    uint vB = hb[(size_t)sB * 8 + q];
    a0 += blo(vA) + blo(vB);
    a1 += bhi(vA) + bhi(vB);
  }
  if (j < dg) {
    int s = perm[o + j];
    uint v = hb[(size_t)s * 8 + q];
    a0 += blo(v);
    a1 += bhi(v);
  }
#pragma unroll
  for (int d = 8; d <= 32; d <<= 1) {
    a0 += __shfl_xor(a0, d);
    a1 += __shfl_xor(a1, d);
  }
  float rd = 1.0f / fmaxf((float)dg, 1.0f);
  float2 ob = *(const float2*)(b2 + q * 2);
  float2 os = *(const float2*)(oself + (size_t)node * 16 + q * 2);
  float l0 = os.x + ob.x + a0 * rd;
  float l1 = os.y + ob.y + a1 * rd;
  // log_softmax over 16 feats (8 lanes x 2 each)
  float m = fmaxf(l0, l1);
#pragma unroll
  for (int d = 1; d <= 4; d <<= 1) m = fmaxf(m, __shfl_xor(m, d));
  float s = __expf(l0 - m) + __expf(l1 - m);
#pragma unroll
  for (int d = 1; d <= 4; d <<= 1) s += __shfl_xor(s, d);
  if (slot == 0) {
    float ls = logf(s);
    float2 r;
    r.x = l0 - m - ls;
    r.y = l1 - m - ls;
    *(float2*)(out + (size_t)node * 16 + q * 2) = r;
  }
}

// ---------------------------------------------------------------------------
extern "C" void kernel_launch(void* const* d_in, const int* in_sizes, int n_in,
                              void* d_out, int out_size, void* d_ws, size_t ws_size,
                              hipStream_t stream) {
  const float* x   = (const float*)d_in[0];
  const int*   src = (const int*)d_in[1];
  const int*   dst = (const int*)d_in[2];
  const float* ws1 = (const float*)d_in[3];
  const float* wn1 = (const float*)d_in[4];
  const float* b1  = (const float*)d_in[5];
  const float* ws2 = (const float*)d_in[6];
  const float* wn2 = (const float*)d_in[7];
  const float* b2  = (const float*)d_in[8];
  float* out = (float*)d_out;

  // workspace layout
  char* p = (char*)d_ws;
  int* deg   = (int*)p;  p += (size_t)NN * 4;
  int* off   = (int*)p;  p += (size_t)NN * 4;
  int* hist  = (int*)p;  p += (size_t)NH * 4;            // bucket-major, scanned in place
  int* hist2 = (int*)p;  p += (size_t)NH * 4;            // block-major
  int* sums  = (int*)p;  p += (size_t)((NSB + 31) & ~31) * 4;
  unsigned int* ebuf = (unsigned int*)p; p += (size_t)NE * 4;
  int* perm = (int*)p;  p += (size_t)NE * 4;
  uint* xh   = (uint*)p; p += (size_t)NN * 64 * 4;       // bf16 x, row-major
  uint* m1h  = (uint*)p; p += (size_t)NN * 64 * 4;       // bf16 mean1, row-major
  uint* xq   = (uint*)p; p += (size_t)NN * 32 * 4;       // fp8 x (12.8 MB)
  uint* w1t  = (uint*)p; p += (size_t)128 * 128 * 4;     // bf16 [ws1;wn1]^T
  uint* w2t  = (uint*)p; p += (size_t)32 * 64 * 4;       // bf16 [ws2|wn2]^T
  ushort_t* h2b = (ushort_t*)p; p += (size_t)NN * 16 * 2; // bf16 h2 (3.2 MB)
  float* osf    = (float*)p;    p += (size_t)NN * 16 * 4;

  tobf16_kernel<<<(NN * 16 + 255) / 256, 256, 0, stream>>>(x, xh, xq);
  prep_w_kernel<<<(128 * 128 + 32 * 64 + 255) / 256, 256, 0, stream>>>(
      ws1, wn1, ws2, wn2, w1t, w2t);

  histA_kernel<<<NBLK, 1024, 0, stream>>>(dst, hist2);
  transpose_kernel<<<dim3((NBUCK + 31) / 32, NBLK / 32), 1024, 0, stream>>>(
      hist2, hist);
  scan_sums_kernel<<<NSB, 1024, 0, stream>>>(hist, sums);
  scan_tops_kernel<<<1, 512, 0, stream>>>(sums);
  scan_apply_kernel<<<NSB, 1024, 0, stream>>>(hist, sums);
  scatter3_kernel<<<NBLK, 1024, 0, stream>>>(src, dst, hist, ebuf);
  bucket_sort_kernel<<<NBUCK, 256, 0, stream>>>(ebuf, hist, deg, off, perm);

  mean1_kernel<<<(NN + 3) / 4, 256, 0, stream>>>(xq, off, deg, perm, m1h);

  gemm12_kernel<<<(NN + 255) / 256, 256, 0, stream>>>(
      xh, m1h, w1t, w2t, b1, osf, h2b);

  mean2_kernel<<<(NN + 3) / 4, 256, 0, stream>>>(h2b, off, deg, perm, osf, b2, out);
}

// Round 19
// 169.664 us; speedup vs baseline: 1.1336x; 1.0023x over previous
//
#include <hip/hip_runtime.h>
#include <math.h>

#define NN 100000
#define NE 1600000
#define BSZ 64                          // dst nodes per bucket
#define NBUCK ((NN + BSZ - 1) / BSZ)    // 1563
#define NBLK 256                        // scatter blocks / hist columns
#define CHUNK ((NE + NBLK - 1) / NBLK)  // 6250 edges per block
#define NH (NBUCK * NBLK)               // 400128 hist entries
#define NSB ((NH + 1023) / 1024)        // 391 scan blocks

typedef unsigned int uint;
typedef unsigned short ushort_t;
typedef float f32x2 __attribute__((ext_vector_type(2)));
typedef float f32x4 __attribute__((ext_vector_type(4)));
typedef short s16x8 __attribute__((ext_vector_type(8)));

union U4S8 { uint4 u; s16x8 s; };

// bf16 helpers (RNE pack, shift decode)
__device__ inline uint bf16_1(float f) {
  uint u = __float_as_uint(f);
  return (u + 0x7FFFu + ((u >> 16) & 1u)) >> 16;
}
__device__ inline uint bf16_2(float lo, float hi) {
  return bf16_1(lo) | (bf16_1(hi) << 16);
}
__device__ inline float blo(uint u) { return __uint_as_float(u << 16); }
__device__ inline float bhi(uint u) { return __uint_as_float(u & 0xFFFF0000u); }

__device__ inline f32x4 mfma_bf16(uint4 a, uint4 b, f32x4 c) {
  U4S8 ua, ub; ua.u = a; ub.u = b;
  return __builtin_amdgcn_mfma_f32_16x16x32_bf16(ua.s, ub.s, c, 0, 0, 0);
}

// ---------------------------------------------------------------------------
// Fused input prep: x -> xh (bf16) + xq (fp8); tail blocks pack w1t/w2t.
// ---------------------------------------------------------------------------
__global__ __launch_bounds__(256) void prep_kernel(
    const float* __restrict__ x, uint* __restrict__ xh, uint* __restrict__ xq,
    const float* __restrict__ ws1, const float* __restrict__ wn1,
    const float* __restrict__ ws2, const float* __restrict__ wn2,
    uint* __restrict__ w1t, uint* __restrict__ w2t) {
  int i = blockIdx.x * 256 + threadIdx.x;
  if (i < NN * 16) {
    const float4* p = (const float4*)x + (size_t)i * 2;
    float4 a = p[0], b = p[1];
    uint4 o;
    o.x = bf16_2(a.x, a.y);
    o.y = bf16_2(a.z, a.w);
    o.z = bf16_2(b.x, b.y);
    o.w = bf16_2(b.z, b.w);
    ((uint4*)xh)[i] = o;
    int q0 = __builtin_amdgcn_cvt_pk_fp8_f32(a.x, a.y, 0, false);
    q0 = __builtin_amdgcn_cvt_pk_fp8_f32(a.z, a.w, q0, true);
    int q1 = __builtin_amdgcn_cvt_pk_fp8_f32(b.x, b.y, 0, false);
    q1 = __builtin_amdgcn_cvt_pk_fp8_f32(b.z, b.w, q1, true);
    uint2 oq; oq.x = (uint)q0; oq.y = (uint)q1;
    int r = i >> 4;
    int u = (i & 15) * 2;
    *(uint2*)(xq + (size_t)r * 32 + u) = oq;
  } else {
    int idx = i - NN * 16;
    if (idx < 128 * 128) {
      int col = idx >> 7, ku = idx & 127;
      int k = ku * 2;
      const float* w = (k < 128) ? ws1 : wn1;
      int kk = (k < 128) ? k : (k - 128);
      w1t[idx] = bf16_2(w[(size_t)kk * 128 + col], w[(size_t)(kk + 1) * 128 + col]);
    } else if (idx < 128 * 128 + 32 * 64) {
      int j = idx - 128 * 128;
      int col = j >> 6, ku = j & 63;
      int k = ku * 2;
      const float* w = (col < 16) ? ws2 : wn2;
      int c = col & 15;
      w2t[j] = bf16_2(w[(size_t)k * 16 + c], w[(size_t)(k + 1) * 16 + c]);
    }
  }
}

// ---------------------------------------------------------------------------
// Pass A: per-block bucket histogram, LDS atomics only, coalesced output.
// ---------------------------------------------------------------------------
__global__ __launch_bounds__(1024) void histA_kernel(
    const int* __restrict__ dst, int* __restrict__ hist2) {
  __shared__ int lh[NBUCK];
  int tid = threadIdx.x;
  int b = blockIdx.x;
  for (int i = tid; i < NBUCK; i += 1024) lh[i] = 0;
  __syncthreads();
  int e0 = b * CHUNK, e1 = min(e0 + CHUNK, NE);
  for (int e = e0 + tid; e < e1; e += 1024) {
    atomicAdd(&lh[dst[e] >> 6], 1);
  }
  __syncthreads();
  for (int i = tid; i < NBUCK; i += 1024)
    hist2[(size_t)b * NBUCK + i] = lh[i];
}

// ---------------------------------------------------------------------------
// Transpose hist2[NBLK][NBUCK] -> hist[NBUCK][NBLK].
// ---------------------------------------------------------------------------
__global__ __launch_bounds__(1024) void transpose_kernel(
    const int* __restrict__ hist2, int* __restrict__ hist) {
  __shared__ int t[32][33];
  int tx = threadIdx.x & 31, ty = threadIdx.x >> 5;
  int i = blockIdx.x * 32 + tx;
  int b = blockIdx.y * 32 + ty;
  if (i < NBUCK) t[ty][tx] = hist2[(size_t)b * NBUCK + i];
  __syncthreads();
  int i2 = blockIdx.x * 32 + ty;
  int b2 = blockIdx.y * 32 + tx;
  if (i2 < NBUCK) hist[(size_t)i2 * NBLK + b2] = t[tx][ty];
}

// ---------------------------------------------------------------------------
// Multi-block exclusive scan over hist[NH] (in-place), 3 kernels.
// ---------------------------------------------------------------------------
__global__ __launch_bounds__(1024) void scan_sums_kernel(
    const int* __restrict__ hist, int* __restrict__ sums) {
  __shared__ int sdata[1024];
  int i = blockIdx.x * 1024 + threadIdx.x;
  sdata[threadIdx.x] = (i < NH) ? hist[i] : 0;
  __syncthreads();
#pragma unroll
  for (int s = 512; s > 0; s >>= 1) {
    if (threadIdx.x < s) sdata[threadIdx.x] += sdata[threadIdx.x + s];
    __syncthreads();
  }
  if (threadIdx.x == 0) sums[blockIdx.x] = sdata[0];
}

__global__ __launch_bounds__(512) void scan_tops_kernel(int* __restrict__ sums) {
  __shared__ int buf[2][512];
  int tid = threadIdx.x;
  int v = (tid < NSB) ? sums[tid] : 0;
  buf[0][tid] = v;
  __syncthreads();
  int pp = 0;
#pragma unroll
  for (int d = 1; d < 512; d <<= 1) {
    buf[pp ^ 1][tid] = buf[pp][tid] + ((tid >= d) ? buf[pp][tid - d] : 0);
    pp ^= 1;
    __syncthreads();
  }
  if (tid < NSB) sums[tid] = buf[pp][tid] - v;  // exclusive
}

__global__ __launch_bounds__(1024) void scan_apply_kernel(
    int* __restrict__ hist, const int* __restrict__ sums) {
  __shared__ int buf[2][1024];
  int tid = threadIdx.x;
  int i = blockIdx.x * 1024 + tid;
  int v = (i < NH) ? hist[i] : 0;
  buf[0][tid] = v;
  __syncthreads();
  int pp = 0;
#pragma unroll
  for (int d = 1; d < 1024; d <<= 1) {
    buf[pp ^ 1][tid] = buf[pp][tid] + ((tid >= d) ? buf[pp][tid - d] : 0);
    pp ^= 1;
    __syncthreads();
  }
  if (i < NH) hist[i] = sums[blockIdx.x] + buf[pp][tid] - v;  // exclusive
}

// ---------------------------------------------------------------------------
// Pass C: contention-free scatter via scanned per-(bucket,block) cursors.
// ---------------------------------------------------------------------------
__global__ __launch_bounds__(1024) void scatter3_kernel(
    const int* __restrict__ src, const int* __restrict__ dst,
    const int* __restrict__ scanned, unsigned int* __restrict__ ebuf) {
  __shared__ int cur[NBUCK];
  int tid = threadIdx.x;
  int b = blockIdx.x;
  for (int i = tid; i < NBUCK; i += 1024) cur[i] = scanned[i * NBLK + b];
  __syncthreads();
  int e0 = b * CHUNK, e1 = min(e0 + CHUNK, NE);
  for (int e = e0 + tid; e < e1; e += 1024) {
    int d = dst[e];
    int p = atomicAdd(&cur[d >> 6], 1);
    ebuf[p] = ((unsigned int)(d & 63) << 17) | (unsigned int)src[e];
  }
}

// ---------------------------------------------------------------------------
// Per-bucket counting sort, two-pass (computes deg + off, no global atomics).
// ---------------------------------------------------------------------------
__global__ __launch_bounds__(256) void bucket_sort_kernel(
    const unsigned int* __restrict__ ebuf, const int* __restrict__ scanned,
    int* __restrict__ deg, int* __restrict__ off, int* __restrict__ perm) {
  __shared__ int cnt[BSZ];
  __shared__ int loc_off[BSZ];
  int tid = threadIdx.x;
  int b = blockIdx.x;
  int e0 = scanned[b * NBLK];
  int e1 = (b + 1 < NBUCK) ? scanned[(b + 1) * NBLK] : NE;

  if (tid < BSZ) cnt[tid] = 0;
  __syncthreads();
  for (int e = e0 + tid; e < e1; e += 256)
    atomicAdd(&cnt[ebuf[e] >> 17], 1);
  __syncthreads();

  if (tid < BSZ) {   // threads 0..63 = one wave
    int v = cnt[tid];
    int incl = v;
#pragma unroll
    for (int d = 1; d < 64; d <<= 1) {
      int t = __shfl_up(incl, d);
      if (tid >= d) incl += t;
    }
    int excl = incl - v;
    loc_off[tid] = e0 + excl;
    int node = b * BSZ + tid;
    if (node < NN) { off[node] = e0 + excl; deg[node] = v; }
    cnt[tid] = 0;
  }
  __syncthreads();

  for (int e = e0 + tid; e < e1; e += 256) {
    unsigned int pk = ebuf[e];
    int dl = pk >> 17;
    int p = loc_off[dl] + atomicAdd(&cnt[dl], 1);
    perm[p] = (int)(pk & 0x1FFFF);
  }
}

// ---------------------------------------------------------------------------
// Layer-1 mean aggregation (measured floor form): one wave per node.
// ---------------------------------------------------------------------------
__global__ __launch_bounds__(256) void mean1_kernel(
    const uint* __restrict__ xq, const int* __restrict__ off,
    const int* __restrict__ deg, const int* __restrict__ perm,
    uint* __restrict__ m1h) {
  int node = blockIdx.x * 4 + (threadIdx.x >> 6);
  int lane = threadIdx.x & 63;
  if (node >= NN) return;
  int o = off[node], dg = deg[node];
  int slot = lane >> 5;   // 0 or 1
  int q = lane & 31;      // uint within the 32-uint fp8 row
  f32x2 a0 = {0.f, 0.f}, a1 = {0.f, 0.f};
  int j = 0;
  for (; j + 8 <= dg; j += 8) {
    int sA = perm[o + j + slot];
    int sB = perm[o + j + 2 + slot];
    int sC = perm[o + j + 4 + slot];
    int sD = perm[o + j + 6 + slot];
    uint vA = xq[(size_t)sA * 32 + q];
    uint vB = xq[(size_t)sB * 32 + q];
    uint vC = xq[(size_t)sC * 32 + q];
    uint vD = xq[(size_t)sD * 32 + q];
    a0 += __builtin_amdgcn_cvt_pk_f32_fp8(vA, 0);
    a1 += __builtin_amdgcn_cvt_pk_f32_fp8(vA, 1);
    a0 += __builtin_amdgcn_cvt_pk_f32_fp8(vB, 0);
    a1 += __builtin_amdgcn_cvt_pk_f32_fp8(vB, 1);
    a0 += __builtin_amdgcn_cvt_pk_f32_fp8(vC, 0);
    a1 += __builtin_amdgcn_cvt_pk_f32_fp8(vC, 1);
    a0 += __builtin_amdgcn_cvt_pk_f32_fp8(vD, 0);
    a1 += __builtin_amdgcn_cvt_pk_f32_fp8(vD, 1);
  }
  for (; j + 2 <= dg; j += 2) {
    int s = perm[o + j + slot];
    uint v = xq[(size_t)s * 32 + q];
    a0 += __builtin_amdgcn_cvt_pk_f32_fp8(v, 0);
    a1 += __builtin_amdgcn_cvt_pk_f32_fp8(v, 1);
  }
  if (j < dg && slot == 0) {
    int s = perm[o + j];
    uint v = xq[(size_t)s * 32 + q];
    a0 += __builtin_amdgcn_cvt_pk_f32_fp8(v, 0);
    a1 += __builtin_amdgcn_cvt_pk_f32_fp8(v, 1);
  }
  a0.x += __shfl_xor(a0.x, 32);
  a0.y += __shfl_xor(a0.y, 32);
  a1.x += __shfl_xor(a1.x, 32);
  a1.y += __shfl_xor(a1.y, 32);
  if (slot == 0) {
    float rd = 1.0f / fmaxf((float)dg, 1.0f);
    uint2 o2;
    o2.x = bf16_2(a0.x * rd, a0.y * rd);
    o2.y = bf16_2(a1.x * rd, a1.y * rd);
    *(uint2*)(m1h + (size_t)node * 64 + q * 2) = o2;
  }
}

// ---------------------------------------------------------------------------
// FUSED GEMM1+GEMM2 (MFMA bf16), 512 rows per block (two 256-row tile
// passes reusing the staged w1t -> staging traffic halved), async
// global_load_lds width-16 staging with pre-swizzled global source
// (LDS dest linear; src chunk = cs ^ (row&7)).
// ---------------------------------------------------------------------------
__global__ __launch_bounds__(256) void gemm12_kernel(
    const uint* __restrict__ xh, const uint* __restrict__ m1h,
    const uint* __restrict__ w1t, const uint* __restrict__ w2t,
    const float* __restrict__ b1, float* __restrict__ oself,
    ushort_t* __restrict__ h2b) {
  __shared__ uint lds_w[128 * 128];   // 64 KB; reused as ushort h-tile
  int tid = threadIdx.x;
  int wv = tid >> 6;
  int lane = tid & 63;

  // async stage w1t, pre-swizzled source: LDS uint4 g holds global chunk
  // (g>>5)*32 + ((g&31) ^ ((g>>5)&7)).
  {
#pragma unroll
    for (int i = 0; i < 16; i++) {
      int g = tid + i * 256;              // lanes of a wave are consecutive
      int row = g >> 5, cs = g & 31;
      int gsrc = row * 32 + (cs ^ (row & 7));
      __builtin_amdgcn_global_load_lds(
          (const uint*)((const uint4*)w1t + gsrc),
          &lds_w[(size_t)(wv * 64 + i * 256) * 4], 16, 0, 0);
    }
  }
  __syncthreads();

  int lr = lane & 15, lk = lane >> 4;
  float bias[8];
#pragma unroll
  for (int ct = 0; ct < 8; ct++) bias[ct] = b1[ct * 16 + lr];

  for (int half = 0; half < 2; half++) {
    int r0 = blockIdx.x * 512 + half * 256 + wv * 64;

    f32x4 acc[4][8];
#pragma unroll
    for (int i = 0; i < 4; i++)
#pragma unroll
      for (int j = 0; j < 8; j++) acc[i][j] = (f32x4){0.f, 0.f, 0.f, 0.f};

#pragma unroll
    for (int ks = 0; ks < 8; ks++) {
      const uint* A = (ks < 4) ? xh : m1h;
      int ku = (ks & 3) * 16 + lk * 4;
      uint4 a[4];
#pragma unroll
      for (int rt = 0; rt < 4; rt++) {
        int row = r0 + rt * 16 + lr;
        if (row >= NN) row = NN - 1;
        a[rt] = *(const uint4*)(A + (size_t)row * 64 + ku);
      }
      int cbase = ks * 4 + lk;
#pragma unroll
      for (int ct = 0; ct < 8; ct++) {
        int brow = ct * 16 + lr;
        int cs = cbase ^ (lr & 7);
        uint4 bu = *(const uint4*)&lds_w[brow * 128 + cs * 4];
#pragma unroll
        for (int rt = 0; rt < 4; rt++)
          acc[rt][ct] = mfma_bf16(a[rt], bu, acc[rt][ct]);
      }
    }

    // write epilogue directly to global: oself fp32, h2 bf16; and gemm2
    // from registers via LDS h-tile (upper 32KB region per half to avoid
    // clobbering w1t? No: w1t fully consumed for this half's MFMA, but the
    // second half still needs it -> use a dedicated h-tile region? LDS is
    // exactly 64KB. Solution: keep h in the SAME lds_w but only between
    // halves barrier-restore is impossible; instead run gemm2 from
    // registers via per-wave LDS scratch of 16KB at a fixed offset per
    // wave, sized 64 rows x 128 cols bf16 = 16KB -> 4 waves x 16KB = 64KB
    // = whole LDS. So: barrier, overwrite, gemm2, barrier, re-stage w1t
    // for half 1. Staging is async + L2-hot, cost ~2us total extra.
    __syncthreads();
    ushort_t* lds_h = (ushort_t*)lds_w;
#pragma unroll
    for (int rt = 0; rt < 4; rt++) {
#pragma unroll
      for (int r = 0; r < 4; r++) {
        int rel = wv * 64 + rt * 16 + lk * 4 + r;
#pragma unroll
        for (int ct = 0; ct < 8; ct++) {
          int col = ct * 16 + lr;
          float v = fmaxf(acc[rt][ct][r] + bias[ct], 0.0f);
          int chunk = col >> 3;
          int cs = chunk ^ ((rel & 7) << 1);
          lds_h[rel * 128 + (cs << 3) + (col & 7)] = (ushort_t)bf16_1(v);
        }
      }
    }

    f32x4 acc2[4][2];
#pragma unroll
    for (int i = 0; i < 4; i++)
#pragma unroll
      for (int j = 0; j < 2; j++) acc2[i][j] = (f32x4){0.f, 0.f, 0.f, 0.f};

#pragma unroll
    for (int ks = 0; ks < 4; ks++) {
      uint4 a[4];
#pragma unroll
      for (int rt = 0; rt < 4; rt++) {
        int rel = wv * 64 + rt * 16 + lr;
        int chunk = ks * 4 + lk;
        int cs = chunk ^ ((rel & 7) << 1);
        a[rt] = *(const uint4*)&lds_h[rel * 128 + (cs << 3)];
      }
#pragma unroll
      for (int ct = 0; ct < 2; ct++) {
        uint4 bu = *(const uint4*)(w2t + (size_t)(ct * 16 + lr) * 64 + ks * 16 + lk * 4);
        acc2[0][ct] = mfma_bf16(a[0], bu, acc2[0][ct]);
        acc2[1][ct] = mfma_bf16(a[1], bu, acc2[1][ct]);
        acc2[2][ct] = mfma_bf16(a[2], bu, acc2[2][ct]);
        acc2[3][ct] = mfma_bf16(a[3], bu, acc2[3][ct]);
      }
    }

#pragma unroll
    for (int rt = 0; rt < 4; rt++) {
#pragma unroll
      for (int r = 0; r < 4; r++) {
        int row = r0 + rt * 16 + lk * 4 + r;
        if (row < NN) {
          oself[(size_t)row * 16 + lr] = acc2[rt][0][r];
          h2b[(size_t)row * 16 + lr]  = (ushort_t)bf16_1(acc2[rt][1][r]);
        }
      }
    }

    if (half == 0) {
      __syncthreads();   // all gemm2 LDS reads done
      // re-stage w1t (async, L2-hot) for the second half
#pragma unroll
      for (int i = 0; i < 16; i++) {
        int g = tid + i * 256;
        int row = g >> 5, cs = g & 31;
        int gsrc = row * 32 + (cs ^ (row & 7));
        __builtin_amdgcn_global_load_lds(
            (const uint*)((const uint4*)w1t + gsrc),
            &lds_w[(size_t)(wv * 64 + i * 256) * 4], 16, 0, 0);
      }
      __syncthreads();
    }
  }
}

// ---------------------------------------------------------------------------
// Layer-2 mean aggregation from bf16 rows (32B, L2-resident) + log_softmax.
// ---------------------------------------------------------------------------
__global__ __launch_bounds__(256) void mean2_kernel(
    const ushort_t* __restrict__ h2b, const int* __restrict__ off,
    const int* __restrict__ deg, const int* __restrict__ perm,
    const float* __restrict__ oself, const float* __restrict__ b2,
    float* __restrict__ out) {
  int node = blockIdx.x * 4 + (threadIdx.x >> 6);
  int lane = threadIdx.x & 63;
  if (node >= NN) return;
  int o = off[node], dg = deg[node];
  int slot = lane >> 3;   // 8 edge slots
  int q = lane & 7;       // owned uint (feats 2q, 2q+1)
  const uint* hb = (const uint*)h2b;
  float a0 = 0.f, a1 = 0.f;
  int j = slot;
  for (; j + 8 < dg; j += 16) {
    int sA = perm[o + j];
    int sB = perm[o + j + 8];
    uint vA = hb[(size_t)sA * 8 + q];
    uint vB = hb[(size_t)sB * 8 + q];
    a0 += blo(vA) + blo(vB);
    a1 += bhi(vA) + bhi(vB);
  }
  if (j < dg) {
    int s = perm[o + j];
    uint v = hb[(size_t)s * 8 + q];
    a0 += blo(v);
    a1 += bhi(v);
  }
#pragma unroll
  for (int d = 8; d <= 32; d <<= 1) {
    a0 += __shfl_xor(a0, d);
    a1 += __shfl_xor(a1, d);
  }
  float rd = 1.0f / fmaxf((float)dg, 1.0f);
  float2 ob = *(const float2*)(b2 + q * 2);
  float2 os = *(const float2*)(oself + (size_t)node * 16 + q * 2);
  float l0 = os.x + ob.x + a0 * rd;
  float l1 = os.y + ob.y + a1 * rd;
  float m = fmaxf(l0, l1);
#pragma unroll
  for (int d = 1; d <= 4; d <<= 1) m = fmaxf(m, __shfl_xor(m, d));
  float s = __expf(l0 - m) + __expf(l1 - m);
#pragma unroll
  for (int d = 1; d <= 4; d <<= 1) s += __shfl_xor(s, d);
  if (slot == 0) {
    float ls = logf(s);
    float2 r;
    r.x = l0 - m - ls;
    r.y = l1 - m - ls;
    *(float2*)(out + (size_t)node * 16 + q * 2) = r;
  }
}

// ---------------------------------------------------------------------------
extern "C" void kernel_launch(void* const* d_in, const int* in_sizes, int n_in,
                              void* d_out, int out_size, void* d_ws, size_t ws_size,
                              hipStream_t stream) {
  const float* x   = (const float*)d_in[0];
  const int*   src = (const int*)d_in[1];
  const int*   dst = (const int*)d_in[2];
  const float* ws1 = (const float*)d_in[3];
  const float* wn1 = (const float*)d_in[4];
  const float* b1  = (const float*)d_in[5];
  const float* ws2 = (const float*)d_in[6];
  const float* wn2 = (const float*)d_in[7];
  const float* b2  = (const float*)d_in[8];
  float* out = (float*)d_out;

  // workspace layout
  char* p = (char*)d_ws;
  int* deg   = (int*)p;  p += (size_t)NN * 4;
  int* off   = (int*)p;  p += (size_t)NN * 4;
  int* hist  = (int*)p;  p += (size_t)NH * 4;            // bucket-major, scanned in place
  int* hist2 = (int*)p;  p += (size_t)NH * 4;            // block-major
  int* sums  = (int*)p;  p += (size_t)((NSB + 31) & ~31) * 4;
  unsigned int* ebuf = (unsigned int*)p; p += (size_t)NE * 4;
  int* perm = (int*)p;  p += (size_t)NE * 4;
  uint* xh   = (uint*)p; p += (size_t)NN * 64 * 4;       // bf16 x, row-major
  uint* m1h  = (uint*)p; p += (size_t)NN * 64 * 4;       // bf16 mean1, row-major
  uint* xq   = (uint*)p; p += (size_t)NN * 32 * 4;       // fp8 x (12.8 MB)
  uint* w1t  = (uint*)p; p += (size_t)128 * 128 * 4;     // bf16 [ws1;wn1]^T
  uint* w2t  = (uint*)p; p += (size_t)32 * 64 * 4;       // bf16 [ws2|wn2]^T
  ushort_t* h2b = (ushort_t*)p; p += (size_t)NN * 16 * 2; // bf16 h2 (3.2 MB)
  float* osf    = (float*)p;    p += (size_t)NN * 16 * 4;

  prep_kernel<<<(NN * 16 + 128 * 128 + 32 * 64 + 255) / 256, 256, 0, stream>>>(
      x, xh, xq, ws1, wn1, ws2, wn2, w1t, w2t);

  histA_kernel<<<NBLK, 1024, 0, stream>>>(dst, hist2);
  transpose_kernel<<<dim3((NBUCK + 31) / 32, NBLK / 32), 1024, 0, stream>>>(
      hist2, hist);
  scan_sums_kernel<<<NSB, 1024, 0, stream>>>(hist, sums);
  scan_tops_kernel<<<1, 512, 0, stream>>>(sums);
  scan_apply_kernel<<<NSB, 1024, 0, stream>>>(hist, sums);
  scatter3_kernel<<<NBLK, 1024, 0, stream>>>(src, dst, hist, ebuf);
  bucket_sort_kernel<<<NBUCK, 256, 0, stream>>>(ebuf, hist, deg, off, perm);

  mean1_kernel<<<(NN + 3) / 4, 256, 0, stream>>>(xq, off, deg, perm, m1h);

  gemm12_kernel<<<(NN + 511) / 512, 256, 0, stream>>>(
      xh, m1h, w1t, w2t, b1, osf, h2b);

  mean2_kernel<<<(NN + 3) / 4, 256, 0, stream>>>(h2b, off, deg, perm, osf, b2, out);
}